// Round 9
// baseline (114.635 us; speedup 1.0000x reference)
//
#include <hip/hip_runtime.h>
#include <cmath>

// Problem constants (fixed by setup_inputs)
constexpr int NN = 2;       // batch
constexpr int LL = 2048;    // sequence
constexpr int HH = 8;       // heads
constexpr int EE = 32;      // feature dim == value dim
constexpr int CC = 32;      // chunk length
constexpr int NCH = LL / CC;       // 64 chunks per (n,h)
constexpr int NB  = NN * HH * NCH; // 1024 blocks
constexpr int BWD = 10;     // softmax bandwidth
// bf16 record per chunk (shorts): St1[d][e] 32x32, k1[32], St2, k2
// RAW per-chunk sums (no prefix pass): fused sums predecessors itself.
constexpr int REC  = 2 * (EE * EE + EE);   // 2112 shorts = 4224 B
constexpr int R16  = REC * 2 / 16;         // 264 16-byte slots
constexpr int OFF_S1 = 0, OFF_K1 = 1024, OFF_S2 = 1056, OFF_K2 = 2080; // short idx
constexpr int SK = EE + 4;   // 36: float4-aligned f32 row stride (144 B)
constexpr int SB = 40;       // bf16 LDS row stride (80 B, 16B-aligned rows)

using f32x16 = __attribute__((ext_vector_type(16))) float;
using s16x8  = __attribute__((ext_vector_type(8)))  short;

__device__ __forceinline__ float elu1(float x) {
    return x > 0.f ? x + 1.f : __expf(x);   // elu(x)+1
}
// f32 -> bf16 bits, round-to-nearest-even (inputs finite)
__device__ __forceinline__ unsigned short bfr(float x) {
    union { float f; unsigned u; } v; v.f = x;
    return (unsigned short)((v.u + 0x7FFFu + ((v.u >> 16) & 1u)) >> 16);
}
__device__ __forceinline__ float bf2f(unsigned short b) {
    union { unsigned u; float f; } v; v.u = ((unsigned)b) << 16;
    return v.f;
}
// unpack a packed bf16 pair (low / high half of a dword)
__device__ __forceinline__ float blo(unsigned u) {
    union { unsigned x; float f; } v; v.x = u << 16; return v.f;
}
__device__ __forceinline__ float bhi(unsigned u) {
    union { unsigned x; float f; } v; v.x = u & 0xffff0000u; return v.f;
}

// ---------------- Kernel 1: per-chunk RAW state sums -> bf16 ws --------------
// (unchanged from R7 except comment: records stay raw, no scan pass follows)
__global__ __launch_bounds__(256) void chunksum_kernel(
    const float* __restrict__ Kin, const float* __restrict__ Vin,
    unsigned short* __restrict__ ws)
{
    __shared__ float K1n[CC][SK];
    __shared__ float K2n[CC][SK];
    __shared__ float Vs [CC][SK];

    const int b  = blockIdx.x;
    const int c  = b & (NCH - 1);
    const int nh = b >> 6;
    const int t  = threadIdx.x;
    const int lane = t & 31;
    const int grp  = t >> 5;    // 0..7

    for (int r = grp; r < CC; r += 8) {
        const int l = c * CC + r;
        const int base = ((nh >> 3) * LL + l) * HH * EE + (nh & 7) * EE + lane;
        const float k = Kin[base];
        const float v = Vin[base];
        const float f1 = elu1(k);
        const float f2 = f1 * f1;
        float s1 = f1, s2 = f2;
        #pragma unroll
        for (int m = 1; m < 32; m <<= 1) {
            s1 += __shfl_xor(s1, m, 32);
            s2 += __shfl_xor(s2, m, 32);
        }
        K1n[r][lane] = f1 * __builtin_amdgcn_rcpf(s1);   // s1,s2 > 0
        K2n[r][lane] = f2 * __builtin_amdgcn_rcpf(s2);
        Vs [r][lane] = v;
    }
    __syncthreads();

    const int d  = t >> 3;          // 0..31 (value dim)
    const int e0 = (t & 7) * 4;     // 0..28 (feature dim quad)
    float a1x=0.f,a1y=0.f,a1z=0.f,a1w=0.f;
    float a2x=0.f,a2y=0.f,a2z=0.f,a2w=0.f;
    float k1x=0.f,k1y=0.f,k1z=0.f,k1w=0.f;
    float k2x=0.f,k2y=0.f,k2z=0.f,k2w=0.f;
    for (int j = 0; j < CC; ++j) {
        const float vv = Vs[j][d];                      // broadcast, free
        const float4 k1 = *(const float4*)&K1n[j][e0];
        const float4 k2 = *(const float4*)&K2n[j][e0];
        k1x += k1.x; k1y += k1.y; k1z += k1.z; k1w += k1.w;
        k2x += k2.x; k2y += k2.y; k2z += k2.z; k2w += k2.w;
        a1x += vv * k1.x; a1y += vv * k1.y; a1z += vv * k1.z; a1w += vv * k1.w;
        a2x += vv * k2.x; a2y += vv * k2.y; a2z += vv * k2.z; a2w += vv * k2.w;
    }
    unsigned short* wb = ws + (size_t)b * REC;
    ushort4 o1 = { bfr(a1x), bfr(a1y), bfr(a1z), bfr(a1w) };
    ushort4 o2 = { bfr(a2x), bfr(a2y), bfr(a2z), bfr(a2w) };
    *(ushort4*)&wb[OFF_S1 + d * EE + e0] = o1;
    *(ushort4*)&wb[OFF_S2 + d * EE + e0] = o2;
    if (d == 0) {
        ushort4 s1v = { bfr(k1x), bfr(k1y), bfr(k1z), bfr(k1w) };
        ushort4 s2v = { bfr(k2x), bfr(k2y), bfr(k2z), bfr(k2w) };
        *(ushort4*)&wb[OFF_K1 + e0] = s1v;
        *(ushort4*)&wb[OFF_K2 + e0] = s2v;
    }
}

// accumulate 8 bf16 lanes of one uint4 record-slot into f32 accumulators
#define ACC8(A, V) do { \
    A[0] += blo((V).x); A[1] += bhi((V).x); \
    A[2] += blo((V).y); A[3] += bhi((V).y); \
    A[4] += blo((V).z); A[5] += bhi((V).z); \
    A[6] += blo((V).w); A[7] += bhi((V).w); } while (0)

// ---------------- Kernel 2: band + look-back prefix + linear MFMA ------------
// Prefix kernel DELETED: each block sums its c predecessors' raw records
// (slot-parallel: thread t owns uint4 slot t; t<8 also slot 256+t) in f32,
// pipelined 8-deep, overlapped with Phase A/B latency slack.
// Phase C unchanged from R7 (MFMA chain, verified).
__global__ __launch_bounds__(256) void fused_kernel(
    const float* __restrict__ Qin, const float* __restrict__ Kin,
    const float* __restrict__ Vin,
    const float* __restrict__ W1, const float* __restrict__ W2,
    const float* __restrict__ W3, const unsigned short* __restrict__ ws,
    float* __restrict__ out)
{
    __shared__ float Vs [CC + 9][SK];      // rows l0-9 .. l0+31 (f32, band+V-frags)
    __shared__ __align__(16) unsigned short Qfb[CC][SB];  // bf16 elu1(Q)
    __shared__ __align__(16) unsigned short Kfb[CC][SB];  // bf16 elu1(K), raw
    __shared__ __align__(16) unsigned short Pb1[CC][SB];  // P relayout buffers
    __shared__ __align__(16) unsigned short Pb2[CC][SB];
    __shared__ float Ob1[CC][SK];          // branch outputs (w*z applied)
    __shared__ float Ob2[CC][SK];
    // raw-K (band) and prefix record (linear): disjoint lifetimes
    __shared__ __align__(16) union {
        float kr[(CC + 9) * SK];           // 1476 floats = 5904 B
        unsigned short sp[REC];            // 2112 shorts = 4224 B
    } U;

    const int b  = blockIdx.x;
    const int c  = b & (NCH - 1);
    const int nh = b >> 6;
    const int h  = nh & 7;
    const int n  = nh >> 3;
    const int l0 = c * CC;
    const int t  = threadIdx.x;
    const int lane = t & 31;
    const int grp  = t >> 5;       // 0..7

    // ---------------- Phase A: pure staging (no reductions) -----------------
    for (int r = grp; r < CC; r += 8) {
        const int l = l0 + r;
        const int base = ((n * LL + l) * HH + h) * EE + lane;
        const float k = Kin[base];
        const float v = Vin[base];
        const float q = Qin[base];
        Kfb[r][lane] = bfr(elu1(k));
        Qfb[r][lane] = bfr(elu1(q));
        Vs[9 + r][lane] = v;
        U.kr[(9 + r) * SK + lane] = k;
    }
    // previous 9 rows of raw K,V for the band window
    for (int idx = t; idx < 9 * 32; idx += 256) {
        const int rr = idx >> 5, ln = idx & 31;
        const int l = l0 - 9 + rr;
        float kv = 0.f, vv = 0.f;
        if (l >= 0) {
            const int gbase = ((n * LL + l) * HH + h) * EE + ln;
            kv = Kin[gbase];
            vv = Vin[gbase];
        }
        U.kr[rr * SK + ln] = kv;
        Vs[rr][ln] = vv;
    }

    // ---------------- look-back: exclusive prefix of raw records (f32) ------
    // registers only; overlaps staging-load latency. Result published to U.sp
    // after Phase B (same position the old prefix-record copy used).
    float la[8]; float lb[8];
    #pragma unroll
    for (int i = 0; i < 8; ++i) { la[i] = 0.f; lb[i] = 0.f; }
    {
        const uint4* rb4 = (const uint4*)ws;
        const size_t p0 = (size_t)(b - c) * R16 + t;   // first predecessor, own slot
        const bool tail = (t < 8);
        int j = 0;
        for (; j + 8 <= c; j += 8) {
            uint4 v0 = rb4[p0 + (size_t)(j+0) * R16];
            uint4 v1 = rb4[p0 + (size_t)(j+1) * R16];
            uint4 v2 = rb4[p0 + (size_t)(j+2) * R16];
            uint4 v3 = rb4[p0 + (size_t)(j+3) * R16];
            uint4 v4 = rb4[p0 + (size_t)(j+4) * R16];
            uint4 v5 = rb4[p0 + (size_t)(j+5) * R16];
            uint4 v6 = rb4[p0 + (size_t)(j+6) * R16];
            uint4 v7 = rb4[p0 + (size_t)(j+7) * R16];
            if (tail) {
                uint4 w0 = rb4[p0 + 256 + (size_t)(j+0) * R16];
                uint4 w1 = rb4[p0 + 256 + (size_t)(j+1) * R16];
                uint4 w2 = rb4[p0 + 256 + (size_t)(j+2) * R16];
                uint4 w3 = rb4[p0 + 256 + (size_t)(j+3) * R16];
                uint4 w4 = rb4[p0 + 256 + (size_t)(j+4) * R16];
                uint4 w5 = rb4[p0 + 256 + (size_t)(j+5) * R16];
                uint4 w6 = rb4[p0 + 256 + (size_t)(j+6) * R16];
                uint4 w7 = rb4[p0 + 256 + (size_t)(j+7) * R16];
                ACC8(lb, w0); ACC8(lb, w1); ACC8(lb, w2); ACC8(lb, w3);
                ACC8(lb, w4); ACC8(lb, w5); ACC8(lb, w6); ACC8(lb, w7);
            }
            ACC8(la, v0); ACC8(la, v1); ACC8(la, v2); ACC8(la, v3);
            ACC8(la, v4); ACC8(la, v5); ACC8(la, v6); ACC8(la, v7);
        }
        for (; j < c; ++j) {
            uint4 v = rb4[p0 + (size_t)j * R16];
            if (tail) {
                uint4 w = rb4[p0 + 256 + (size_t)j * R16];
                ACC8(lb, w);
            }
            ACC8(la, v);
        }
    }

    // cluster identity for band and the final store
    const int r   = t >> 3;        // row 0..31
    const int sub = t & 7;
    const int d0  = sub * 4;
    const int l   = l0 + r;

    // raw Q quad in registers (band dot)
    const float4 q4 = *(const float4*)&Qin[((n * LL + l) * HH + h) * EE + d0];
    __syncthreads();

    // ---------------- Phase B: banded ONLINE softmax, cluster f4 (verbatim) --
    float bnd[4];
    {
        const float temp = 0.17677669529663687f;   // 1/sqrt(32)
        float mx = -INFINITY, den = 0.f;
        float sv0 = 0.f, sv1 = 0.f, sv2 = 0.f, sv3 = 0.f;
        #pragma unroll
        for (int jj = 0; jj < BWD; ++jj) {
            const int j = l - (BWD - 1) + jj;   // global key row
            if (j >= 0) {                        // uniform per 8-lane row group
                const float4 k4 = *(const float4*)&U.kr[(r + jj) * SK + d0];
                float p = q4.x*k4.x + q4.y*k4.y + q4.z*k4.z + q4.w*k4.w;
                p += __shfl_xor(p, 1, 8); p += __shfl_xor(p, 2, 8); p += __shfl_xor(p, 4, 8);
                const float s  = p * temp;
                const float mn = fmaxf(mx, s);
                const float c1 = __expf(mx - mn);   // 0 on first iter
                const float c2 = __expf(s - mn);
                const float4 v4 = *(const float4*)&Vs[r + jj][d0];
                den = den * c1 + c2;
                sv0 = sv0 * c1 + c2 * v4.x;
                sv1 = sv1 * c1 + c2 * v4.y;
                sv2 = sv2 * c1 + c2 * v4.z;
                sv3 = sv3 * c1 + c2 * v4.w;
                mx = mn;
            }
        }
        const float inv = 1.f / den;
        const float4 w1 = *(const float4*)&W1[h * EE + d0];
        bnd[0] = w1.x * sv0 * inv; bnd[1] = w1.y * sv1 * inv;
        bnd[2] = w1.z * sv2 * inv; bnd[3] = w1.w * sv3 * inv;
    }
    __syncthreads();   // all reads of U.kr done

    // publish computed exclusive-prefix record into U.sp (bf16 pack)
    {
        uint4 o;
        o.x = (unsigned)bfr(la[0]) | ((unsigned)bfr(la[1]) << 16);
        o.y = (unsigned)bfr(la[2]) | ((unsigned)bfr(la[3]) << 16);
        o.z = (unsigned)bfr(la[4]) | ((unsigned)bfr(la[5]) << 16);
        o.w = (unsigned)bfr(la[6]) | ((unsigned)bfr(la[7]) << 16);
        ((uint4*)U.sp)[t] = o;
        if (t < 8) {
            uint4 ob;
            ob.x = (unsigned)bfr(lb[0]) | ((unsigned)bfr(lb[1]) << 16);
            ob.y = (unsigned)bfr(lb[2]) | ((unsigned)bfr(lb[3]) << 16);
            ob.z = (unsigned)bfr(lb[4]) | ((unsigned)bfr(lb[5]) << 16);
            ob.w = (unsigned)bfr(lb[6]) | ((unsigned)bfr(lb[7]) << 16);
            ((uint4*)U.sp)[256 + t] = ob;
        }
    }
    __syncthreads();

    // ---------------- Phase C: per-branch MFMA chain (waves 0 and 2) --------
    const int wid = t >> 6;
    const int l64 = t & 63;
    const int l31 = l64 & 31;       // = A-row / B-col / C-col
    const int hi5 = l64 >> 5;       // k-half selector within frags

    if ((wid & 1) == 0) {
        const bool b2 = (wid == 2);
        const unsigned short* Spt = U.sp + (b2 ? OFF_S2 : OFF_S1); // St[d][e]
        const unsigned short* kp  = U.sp + (b2 ? OFF_K2 : OFF_K1);
        const float* Wv = b2 ? W3 : W2;
        unsigned short* Pb = b2 ? &Pb2[0][0] : &Pb1[0][0];
        float* Ob = b2 ? &Ob2[0][0] : &Ob1[0][0];

        // A-frags Qf rows; B-frags Kf^T = Kfb row reads (branch2: square both)
        s16x8 qa0 = *(const s16x8*)&Qfb[l31][8 * hi5];
        s16x8 qa1 = *(const s16x8*)&Qfb[l31][16 + 8 * hi5];
        s16x8 kb0 = *(const s16x8*)&Kfb[l31][8 * hi5];
        s16x8 kb1 = *(const s16x8*)&Kfb[l31][16 + 8 * hi5];
        if (b2) {
            #pragma unroll
            for (int i = 0; i < 8; ++i) {
                float f;
                f = bf2f((unsigned short)qa0[i]); qa0[i] = (short)bfr(f * f);
                f = bf2f((unsigned short)qa1[i]); qa1[i] = (short)bfr(f * f);
                f = bf2f((unsigned short)kb0[i]); kb0[i] = (short)bfr(f * f);
                f = bf2f((unsigned short)kb1[i]); kb1[i] = (short)bfr(f * f);
            }
        }
        s16x8 ones;
        #pragma unroll
        for (int i = 0; i < 8; ++i) ones[i] = (short)0x3F80;  // bf16 1.0

        // Dk: every lane holds sk[col] (rowsum of Kf over e, replicated)
        f32x16 Dk = {};
        Dk = __builtin_amdgcn_mfma_f32_32x32x16_bf16(ones, kb0, Dk, 0, 0, 0);
        Dk = __builtin_amdgcn_mfma_f32_32x32x16_bf16(ones, kb1, Dk, 0, 0, 0);
        // P_raw = Qf x Kf^T
        f32x16 P = {};
        P = __builtin_amdgcn_mfma_f32_32x32x16_bf16(qa0, kb0, P, 0, 0, 0);
        P = __builtin_amdgcn_mfma_f32_32x32x16_bf16(qa1, kb1, P, 0, 0, 0);

        // causal mask + per-column normalize (f32) -> row-major bf16 in LDS
        const float ki = __builtin_amdgcn_rcpf(Dk[0]);   // 1/sk[l31], sk>0
        #pragma unroll
        for (int k = 0; k < 16; ++k) {
            const int row = (k & 3) + 8 * (k >> 2) + 4 * hi5;
            Pb[row * SB + l31] = bfr((l31 <= row) ? P[k] * ki : 0.f);
        }
        const s16x8 pa0 = *(const s16x8*)&Pb[l31 * SB + 8 * hi5];
        const s16x8 pa1 = *(const s16x8*)&Pb[l31 * SB + 16 + 8 * hi5];

        // B-frags of V (scalar gather from f32 Vs)
        s16x8 vb0, vb1;
        #pragma unroll
        for (int i = 0; i < 8; ++i) {
            vb0[i] = (short)bfr(Vs[9 + 8 * hi5 + i][l31]);
            vb1[i] = (short)bfr(Vs[9 + 16 + 8 * hi5 + i][l31]);
        }
        // B-frags of S: St[d][e] row-major -> vector reads
        const s16x8 sb0 = *(const s16x8*)&Spt[l31 * EE + 8 * hi5];
        const s16x8 sb1 = *(const s16x8*)&Spt[l31 * EE + 16 + 8 * hi5];
        // B-frags of kp: broadcast vector reads
        const s16x8 rb0 = *(const s16x8*)&kp[8 * hi5];
        const s16x8 rb1 = *(const s16x8*)&kp[16 + 8 * hi5];

        f32x16 A = {};
        A = __builtin_amdgcn_mfma_f32_32x32x16_bf16(pa0, vb0, A, 0, 0, 0);  // triangle
        A = __builtin_amdgcn_mfma_f32_32x32x16_bf16(pa1, vb1, A, 0, 0, 0);
        A = __builtin_amdgcn_mfma_f32_32x32x16_bf16(qa0, sb0, A, 0, 0, 0);  // prefix
        A = __builtin_amdgcn_mfma_f32_32x32x16_bf16(qa1, sb1, A, 0, 0, 0);

        f32x16 Dp = {};
        Dp = __builtin_amdgcn_mfma_f32_32x32x16_bf16(pa0, ones, Dp, 0, 0, 0);
        Dp = __builtin_amdgcn_mfma_f32_32x32x16_bf16(pa1, ones, Dp, 0, 0, 0);
        Dp = __builtin_amdgcn_mfma_f32_32x32x16_bf16(qa0, rb0, Dp, 0, 0, 0);
        Dp = __builtin_amdgcn_mfma_f32_32x32x16_bf16(qa1, rb1, Dp, 0, 0, 0);

        // epilogue: z = 1/dp, output weight -> Ob
        const float wv = Wv[h * EE + l31];
        #pragma unroll
        for (int k = 0; k < 16; ++k) {
            const int row = (k & 3) + 8 * (k >> 2) + 4 * hi5;
            Ob[row * SK + l31] = wv * A[k] * __builtin_amdgcn_rcpf(Dp[k]);
        }
    }
    __syncthreads();

    // ---------------- final combine + single store (cluster mapping) --------
    const float4 o1 = *(const float4*)&Ob1[r][d0];
    const float4 o2 = *(const float4*)&Ob2[r][d0];
    float4 o;
    o.x = bnd[0] + o1.x + o2.x;
    o.y = bnd[1] + o1.y + o2.y;
    o.z = bnd[2] + o1.z + o2.z;
    o.w = bnd[3] + o1.w + o2.w;
    *(float4*)&out[((n * LL + l) * HH + h) * EE + d0] = o;
}

extern "C" void kernel_launch(void* const* d_in, const int* in_sizes, int n_in,
                              void* d_out, int out_size, void* d_ws, size_t ws_size,
                              hipStream_t stream)
{
    (void)in_sizes; (void)n_in; (void)out_size; (void)ws_size;
    const float* Q  = (const float*)d_in[0];
    const float* K  = (const float*)d_in[1];
    const float* V  = (const float*)d_in[2];
    // d_in[3] = key_lengths: cancels mathematically (normalization over E)
    const float* W1 = (const float*)d_in[4];
    const float* W2 = (const float*)d_in[5];
    const float* W3 = (const float*)d_in[6];
    float* out = (float*)d_out;
    unsigned short* ws = (unsigned short*)d_ws;   // NB*REC*2 = ~4.3 MB scratch

    chunksum_kernel<<<NB, 256, 0, stream>>>(K, V, ws);
    fused_kernel   <<<NB, 256, 0, stream>>>(Q, K, V, W1, W2, W3, ws, out);
}

// Round 10
// 90.139 us; speedup vs baseline: 1.2717x; 1.2717x over previous
//
#include <hip/hip_runtime.h>
#include <cmath>

// Problem constants (fixed by setup_inputs)
constexpr int NN = 2;       // batch
constexpr int LL = 2048;    // sequence
constexpr int HH = 8;       // heads
constexpr int EE = 32;      // feature dim == value dim
constexpr int CC = 32;      // chunk length
constexpr int NCH = LL / CC;       // 64 chunks per (n,h)
constexpr int NB  = NN * HH * NCH; // 1024 blocks
constexpr int BWD = 10;     // softmax bandwidth
// bf16 record per chunk (shorts): St1[d][e] 32x32, k1[32], St2, k2
// S stored TRANSPOSED (d-major) so fused's B-frags of S are vector reads.
constexpr int REC  = 2 * (EE * EE + EE);   // 2112 shorts = 4224 B
constexpr int R16  = REC * 2 / 16;         // 264 16-byte slots
constexpr int OFF_S1 = 0, OFF_K1 = 1024, OFF_S2 = 1056, OFF_K2 = 2080; // short idx
constexpr int SK = EE + 4;   // 36: float4-aligned f32 row stride (144 B)
constexpr int SB = 40;       // bf16 LDS row stride (80 B, 16B-aligned rows)

using f32x16 = __attribute__((ext_vector_type(16))) float;
using s16x8  = __attribute__((ext_vector_type(8)))  short;

__device__ __forceinline__ float elu1(float x) {
    return x > 0.f ? x + 1.f : __expf(x);   // elu(x)+1
}
// f32 -> bf16 bits, round-to-nearest-even (inputs finite)
__device__ __forceinline__ unsigned short bfr(float x) {
    union { float f; unsigned u; } v; v.f = x;
    return (unsigned short)((v.u + 0x7FFFu + ((v.u >> 16) & 1u)) >> 16);
}
__device__ __forceinline__ float bf2f(unsigned short b) {
    union { unsigned u; float f; } v; v.u = ((unsigned)b) << 16;
    return v.f;
}

// ---------------- Kernel 1: per-chunk state sums via MFMA -> bf16 ws ---------
// R10: the 96-DS-instr/thread accumulation loop replaced by 8 MFMA.
// Staging writes TRANSPOSED bf16 tiles (K1nT[e][j], K2nT[e][j], VT[d][j]);
// then St = V^T x K1n  (D[row=d][col=e] == record layout) and ks = ones x K1n.
// A frag: row=lane&31, k=8*(lane>>5)+i.  C/D: col=lane&31,
// row=(k&3)+8*(k>>2)+4*hi5.  [R4-verified layouts]
__global__ __launch_bounds__(256) void chunksum_kernel(
    const float* __restrict__ Kin, const float* __restrict__ Vin,
    unsigned short* __restrict__ ws)
{
    __shared__ __align__(16) unsigned short K1T[EE][SB];  // [e][j]
    __shared__ __align__(16) unsigned short K2T[EE][SB];  // [e][j]
    __shared__ __align__(16) unsigned short VT [EE][SB];  // [d][j]

    const int b  = blockIdx.x;
    const int c  = b & (NCH - 1);
    const int nh = b >> 6;
    const int t  = threadIdx.x;
    const int lane = t & 31;
    const int grp  = t >> 5;    // 0..7

    for (int r = grp; r < CC; r += 8) {
        const int l = c * CC + r;
        const int base = ((nh >> 3) * LL + l) * HH * EE + (nh & 7) * EE + lane;
        const float k = Kin[base];
        const float v = Vin[base];
        const float f1 = elu1(k);
        const float f2 = f1 * f1;
        float s1 = f1, s2 = f2;
        #pragma unroll
        for (int m = 1; m < 32; m <<= 1) {
            s1 += __shfl_xor(s1, m, 32);
            s2 += __shfl_xor(s2, m, 32);
        }
        K1T[lane][r] = bfr(f1 * __builtin_amdgcn_rcpf(s1));   // s1,s2 > 0
        K2T[lane][r] = bfr(f2 * __builtin_amdgcn_rcpf(s2));
        VT [lane][r] = bfr(v);
    }
    __syncthreads();

    const int wid = t >> 6;         // 0..3
    const int l64 = t & 63;
    const int l31 = l64 & 31;       // A-row (=d) / C-col (=e)
    const int hi5 = l64 >> 5;       // k-half selector

    if (wid < 2) {                  // wave 0: branch 1, wave 1: branch 2
        const unsigned short* KT = wid ? &K2T[0][0] : &K1T[0][0];
        // A-frags: V^T rows (row=d=l31, k=j-run)
        const s16x8 va0 = *(const s16x8*)&VT[l31][8 * hi5];
        const s16x8 va1 = *(const s16x8*)&VT[l31][16 + 8 * hi5];
        // B-frags: B[k=j][col=e=l31] = K1n[j][e] = K1T[e][j] -> row reads
        const s16x8 kb0 = *(const s16x8*)&KT[l31 * SB + 8 * hi5];
        const s16x8 kb1 = *(const s16x8*)&KT[l31 * SB + 16 + 8 * hi5];
        s16x8 ones;
        #pragma unroll
        for (int i = 0; i < 8; ++i) ones[i] = (short)0x3F80;  // bf16 1.0

        f32x16 S = {};
        S = __builtin_amdgcn_mfma_f32_32x32x16_bf16(va0, kb0, S, 0, 0, 0);
        S = __builtin_amdgcn_mfma_f32_32x32x16_bf16(va1, kb1, S, 0, 0, 0);
        f32x16 Dk = {};
        Dk = __builtin_amdgcn_mfma_f32_32x32x16_bf16(ones, kb0, Dk, 0, 0, 0);
        Dk = __builtin_amdgcn_mfma_f32_32x32x16_bf16(ones, kb1, Dk, 0, 0, 0);

        unsigned short* wb = ws + (size_t)b * REC + (wid ? OFF_S2 : OFF_S1);
        unsigned short* wk = ws + (size_t)b * REC + (wid ? OFF_K2 : OFF_K1);
        #pragma unroll
        for (int k = 0; k < 16; ++k) {
            const int row = (k & 3) + 8 * (k >> 2) + 4 * hi5;   // = d
            wb[row * EE + l31] = bfr(S[k]);
        }
        if (hi5 == 0) wk[l31] = bfr(Dk[0]);   // ks[e], replicated over rows
    }
}

// ---------------- Kernel 2: exclusive prefix over chunks (bf16, f32 carry) --
__global__ __launch_bounds__(192) void prefix_kernel(unsigned short* __restrict__ ws)
{
    const int g = blockIdx.x / 11;
    const int e = (blockIdx.x % 11) * 192 + threadIdx.x;   // 0..2111
    unsigned short* base = ws + (size_t)g * NCH * REC + e;
    float run = 0.f;
    {
        unsigned short v[32];
        #pragma unroll
        for (int c = 0; c < 32; ++c) v[c] = base[(size_t)c * REC];
        #pragma unroll
        for (int c = 0; c < 32; ++c) {
            base[(size_t)c * REC] = bfr(run);
            run += bf2f(v[c]);
        }
    }
    {
        unsigned short v[32];
        #pragma unroll
        for (int c = 0; c < 32; ++c) v[c] = base[(size_t)(32 + c) * REC];
        #pragma unroll
        for (int c = 0; c < 32; ++c) {
            base[(size_t)(32 + c) * REC] = bfr(run);
            run += bf2f(v[c]);
        }
    }
}

// ---------------- Kernel 3: band (scalar) + linear via MFMA ------------------
// R10 delta vs R7: V also staged TRANSPOSED bf16 (Vtb[d][j]) so Phase C's
// V B-frags are vector reads (was 16 scalar ds_read_b32 + 16 cvt per lane).
__global__ __launch_bounds__(256) void fused_kernel(
    const float* __restrict__ Qin, const float* __restrict__ Kin,
    const float* __restrict__ Vin,
    const float* __restrict__ W1, const float* __restrict__ W2,
    const float* __restrict__ W3, const unsigned short* __restrict__ ws,
    float* __restrict__ out)
{
    __shared__ float Vs [CC + 9][SK];      // rows l0-9 .. l0+31 (f32, band)
    __shared__ __align__(16) unsigned short Qfb[CC][SB];  // bf16 elu1(Q)
    __shared__ __align__(16) unsigned short Kfb[CC][SB];  // bf16 elu1(K), raw
    __shared__ __align__(16) unsigned short Vtb[EE][SB];  // bf16 V^T [d][j]
    __shared__ __align__(16) unsigned short Pb1[CC][SB];  // P relayout buffers
    __shared__ __align__(16) unsigned short Pb2[CC][SB];
    __shared__ float Ob1[CC][SK];          // branch outputs (w*z applied)
    __shared__ float Ob2[CC][SK];
    // raw-K (band) and prefix record (linear): disjoint lifetimes
    __shared__ __align__(16) union {
        float kr[(CC + 9) * SK];           // 1476 floats = 5904 B
        unsigned short sp[REC];            // 2112 shorts = 4224 B
    } U;

    const int b  = blockIdx.x;
    const int c  = b & (NCH - 1);
    const int nh = b >> 6;
    const int h  = nh & 7;
    const int n  = nh >> 3;
    const int l0 = c * CC;
    const int t  = threadIdx.x;
    const int lane = t & 31;
    const int grp  = t >> 5;       // 0..7

    // own exclusive-prefix record -> registers early (hides under A/B)
    const uint4* wbv = (const uint4*)(ws + (size_t)b * REC);
    const uint4 s0 = wbv[t];
    uint4 s1 = {0u, 0u, 0u, 0u};
    if (t < R16 - 256) s1 = wbv[256 + t];          // last 8

    // ---------------- Phase A: pure staging (no reductions) -----------------
    for (int r = grp; r < CC; r += 8) {
        const int l = l0 + r;
        const int base = ((n * LL + l) * HH + h) * EE + lane;
        const float k = Kin[base];
        const float v = Vin[base];
        const float q = Qin[base];
        Kfb[r][lane] = bfr(elu1(k));
        Qfb[r][lane] = bfr(elu1(q));
        Vs[9 + r][lane] = v;
        Vtb[lane][r] = bfr(v);
        U.kr[(9 + r) * SK + lane] = k;
    }
    // previous 9 rows of raw K,V for the band window
    for (int idx = t; idx < 9 * 32; idx += 256) {
        const int rr = idx >> 5, ln = idx & 31;
        const int l = l0 - 9 + rr;
        float kv = 0.f, vv = 0.f;
        if (l >= 0) {
            const int gbase = ((n * LL + l) * HH + h) * EE + ln;
            kv = Kin[gbase];
            vv = Vin[gbase];
        }
        U.kr[rr * SK + ln] = kv;
        Vs[rr][ln] = vv;
    }

    // cluster identity for band and the final store
    const int r   = t >> 3;        // row 0..31
    const int sub = t & 7;
    const int d0  = sub * 4;
    const int l   = l0 + r;

    // raw Q quad in registers (band dot)
    const float4 q4 = *(const float4*)&Qin[((n * LL + l) * HH + h) * EE + d0];
    __syncthreads();

    // ---------------- Phase B: banded ONLINE softmax, cluster f4 (verbatim) --
    float bnd[4];
    {
        const float temp = 0.17677669529663687f;   // 1/sqrt(32)
        float mx = -INFINITY, den = 0.f;
        float sv0 = 0.f, sv1 = 0.f, sv2 = 0.f, sv3 = 0.f;
        #pragma unroll
        for (int jj = 0; jj < BWD; ++jj) {
            const int j = l - (BWD - 1) + jj;   // global key row
            if (j >= 0) {                        // uniform per 8-lane row group
                const float4 k4 = *(const float4*)&U.kr[(r + jj) * SK + d0];
                float p = q4.x*k4.x + q4.y*k4.y + q4.z*k4.z + q4.w*k4.w;
                p += __shfl_xor(p, 1, 8); p += __shfl_xor(p, 2, 8); p += __shfl_xor(p, 4, 8);
                const float s  = p * temp;
                const float mn = fmaxf(mx, s);
                const float c1 = __expf(mx - mn);   // 0 on first iter
                const float c2 = __expf(s - mn);
                const float4 v4 = *(const float4*)&Vs[r + jj][d0];
                den = den * c1 + c2;
                sv0 = sv0 * c1 + c2 * v4.x;
                sv1 = sv1 * c1 + c2 * v4.y;
                sv2 = sv2 * c1 + c2 * v4.z;
                sv3 = sv3 * c1 + c2 * v4.w;
                mx = mn;
            }
        }
        const float inv = 1.f / den;
        const float4 w1 = *(const float4*)&W1[h * EE + d0];
        bnd[0] = w1.x * sv0 * inv; bnd[1] = w1.y * sv1 * inv;
        bnd[2] = w1.z * sv2 * inv; bnd[3] = w1.w * sv3 * inv;
    }
    __syncthreads();   // all reads of U.kr done

    // publish own prefix record into U.sp (raw bf16 copy)
    ((uint4*)U.sp)[t] = s0;
    if (t < R16 - 256) ((uint4*)U.sp)[256 + t] = s1;
    __syncthreads();

    // ---------------- Phase C: per-branch MFMA chain (waves 0 and 2) --------
    const int wid = t >> 6;
    const int l64 = t & 63;
    const int l31 = l64 & 31;       // = A-row / B-col / C-col
    const int hi5 = l64 >> 5;       // k-half selector within frags

    if ((wid & 1) == 0) {
        const bool b2 = (wid == 2);
        const unsigned short* Spt = U.sp + (b2 ? OFF_S2 : OFF_S1); // St[d][e]
        const unsigned short* kp  = U.sp + (b2 ? OFF_K2 : OFF_K1);
        const float* Wv = b2 ? W3 : W2;
        unsigned short* Pb = b2 ? &Pb2[0][0] : &Pb1[0][0];
        float* Ob = b2 ? &Ob2[0][0] : &Ob1[0][0];

        // A-frags Qf rows; B-frags Kf^T = Kfb row reads (branch2: square both)
        s16x8 qa0 = *(const s16x8*)&Qfb[l31][8 * hi5];
        s16x8 qa1 = *(const s16x8*)&Qfb[l31][16 + 8 * hi5];
        s16x8 kb0 = *(const s16x8*)&Kfb[l31][8 * hi5];
        s16x8 kb1 = *(const s16x8*)&Kfb[l31][16 + 8 * hi5];
        if (b2) {
            #pragma unroll
            for (int i = 0; i < 8; ++i) {
                float f;
                f = bf2f((unsigned short)qa0[i]); qa0[i] = (short)bfr(f * f);
                f = bf2f((unsigned short)qa1[i]); qa1[i] = (short)bfr(f * f);
                f = bf2f((unsigned short)kb0[i]); kb0[i] = (short)bfr(f * f);
                f = bf2f((unsigned short)kb1[i]); kb1[i] = (short)bfr(f * f);
            }
        }
        s16x8 ones;
        #pragma unroll
        for (int i = 0; i < 8; ++i) ones[i] = (short)0x3F80;  // bf16 1.0

        // Dk: every lane holds sk[col] (rowsum of Kf over e, replicated)
        f32x16 Dk = {};
        Dk = __builtin_amdgcn_mfma_f32_32x32x16_bf16(ones, kb0, Dk, 0, 0, 0);
        Dk = __builtin_amdgcn_mfma_f32_32x32x16_bf16(ones, kb1, Dk, 0, 0, 0);
        // P_raw = Qf x Kf^T
        f32x16 P = {};
        P = __builtin_amdgcn_mfma_f32_32x32x16_bf16(qa0, kb0, P, 0, 0, 0);
        P = __builtin_amdgcn_mfma_f32_32x32x16_bf16(qa1, kb1, P, 0, 0, 0);

        // causal mask + per-column normalize (f32) -> row-major bf16 in LDS
        const float ki = __builtin_amdgcn_rcpf(Dk[0]);   // 1/sk[l31], sk>0
        #pragma unroll
        for (int k = 0; k < 16; ++k) {
            const int row = (k & 3) + 8 * (k >> 2) + 4 * hi5;
            Pb[row * SB + l31] = bfr((l31 <= row) ? P[k] * ki : 0.f);
        }
        const s16x8 pa0 = *(const s16x8*)&Pb[l31 * SB + 8 * hi5];
        const s16x8 pa1 = *(const s16x8*)&Pb[l31 * SB + 16 + 8 * hi5];

        // B-frags of V: B[k=j][col=d=l31] = V[j][d] = Vtb[d][j] -> row reads
        const s16x8 vb0 = *(const s16x8*)&Vtb[l31][8 * hi5];
        const s16x8 vb1 = *(const s16x8*)&Vtb[l31][16 + 8 * hi5];
        // B-frags of S: St[d][e] row-major -> vector reads
        const s16x8 sb0 = *(const s16x8*)&Spt[l31 * EE + 8 * hi5];
        const s16x8 sb1 = *(const s16x8*)&Spt[l31 * EE + 16 + 8 * hi5];
        // B-frags of kp: broadcast vector reads
        const s16x8 rb0 = *(const s16x8*)&kp[8 * hi5];
        const s16x8 rb1 = *(const s16x8*)&kp[16 + 8 * hi5];

        f32x16 A = {};
        A = __builtin_amdgcn_mfma_f32_32x32x16_bf16(pa0, vb0, A, 0, 0, 0);  // triangle
        A = __builtin_amdgcn_mfma_f32_32x32x16_bf16(pa1, vb1, A, 0, 0, 0);
        A = __builtin_amdgcn_mfma_f32_32x32x16_bf16(qa0, sb0, A, 0, 0, 0);  // prefix
        A = __builtin_amdgcn_mfma_f32_32x32x16_bf16(qa1, sb1, A, 0, 0, 0);

        f32x16 Dp = {};
        Dp = __builtin_amdgcn_mfma_f32_32x32x16_bf16(pa0, ones, Dp, 0, 0, 0);
        Dp = __builtin_amdgcn_mfma_f32_32x32x16_bf16(pa1, ones, Dp, 0, 0, 0);
        Dp = __builtin_amdgcn_mfma_f32_32x32x16_bf16(qa0, rb0, Dp, 0, 0, 0);
        Dp = __builtin_amdgcn_mfma_f32_32x32x16_bf16(qa1, rb1, Dp, 0, 0, 0);

        // epilogue: z = 1/dp, output weight -> Ob
        const float wv = Wv[h * EE + l31];
        #pragma unroll
        for (int k = 0; k < 16; ++k) {
            const int row = (k & 3) + 8 * (k >> 2) + 4 * hi5;
            Ob[row * SK + l31] = wv * A[k] * __builtin_amdgcn_rcpf(Dp[k]);
        }
    }
    __syncthreads();

    // ---------------- final combine + single store (cluster mapping) --------
    const float4 o1 = *(const float4*)&Ob1[r][d0];
    const float4 o2 = *(const float4*)&Ob2[r][d0];
    float4 o;
    o.x = bnd[0] + o1.x + o2.x;
    o.y = bnd[1] + o1.y + o2.y;
    o.z = bnd[2] + o1.z + o2.z;
    o.w = bnd[3] + o1.w + o2.w;
    *(float4*)&out[((n * LL + l) * HH + h) * EE + d0] = o;
}

extern "C" void kernel_launch(void* const* d_in, const int* in_sizes, int n_in,
                              void* d_out, int out_size, void* d_ws, size_t ws_size,
                              hipStream_t stream)
{
    (void)in_sizes; (void)n_in; (void)out_size; (void)ws_size;
    const float* Q  = (const float*)d_in[0];
    const float* K  = (const float*)d_in[1];
    const float* V  = (const float*)d_in[2];
    // d_in[3] = key_lengths: cancels mathematically (normalization over E)
    const float* W1 = (const float*)d_in[4];
    const float* W2 = (const float*)d_in[5];
    const float* W3 = (const float*)d_in[6];
    float* out = (float*)d_out;
    unsigned short* ws = (unsigned short*)d_ws;   // NB*REC*2 = ~4.3 MB scratch

    chunksum_kernel<<<NB,           256, 0, stream>>>(K, V, ws);
    prefix_kernel  <<<NN * HH * 11, 192, 0, stream>>>(ws);
    fused_kernel   <<<NB,           256, 0, stream>>>(Q, K, V, W1, W2, W3, ws, out);
}

// Round 12
// 87.717 us; speedup vs baseline: 1.3069x; 1.0276x over previous
//
#include <hip/hip_runtime.h>
#include <cmath>

// Problem constants (fixed by setup_inputs)
constexpr int NN = 2;       // batch
constexpr int LL = 2048;    // sequence
constexpr int HH = 8;       // heads
constexpr int EE = 32;      // feature dim == value dim
constexpr int CC = 32;      // chunk length
constexpr int NCH = LL / CC;       // 64 chunks per (n,h)
constexpr int NB  = NN * HH * NCH; // 1024 blocks
constexpr int BWD = 10;     // softmax bandwidth
// bf16 record per chunk (shorts): St1[d][e] 32x32, k1[32], St2, k2
constexpr int REC  = 2 * (EE * EE + EE);   // 2112 shorts = 4224 B
constexpr int R16  = REC * 2 / 16;         // 264 16-byte slots
constexpr int OFF_S1 = 0, OFF_K1 = 1024, OFF_S2 = 1056, OFF_K2 = 2080; // short idx
constexpr int SK = EE + 4;   // 36: float4-aligned f32 row stride (144 B)
constexpr int SB = 40;       // bf16 LDS row stride (80 B, 16B-aligned rows)
constexpr int VS = 48;       // Vtb/Pband col count (96 B rows, 16B-aligned)

using f32x16 = __attribute__((ext_vector_type(16))) float;
using s16x8  = __attribute__((ext_vector_type(8)))  short;

__device__ __forceinline__ float elu1(float x) {
    return x > 0.f ? x + 1.f : __expf(x);   // elu(x)+1
}
// f32 -> bf16 bits, round-to-nearest-even (inputs finite)
__device__ __forceinline__ unsigned short bfr(float x) {
    union { float f; unsigned u; } v; v.f = x;
    return (unsigned short)((v.u + 0x7FFFu + ((v.u >> 16) & 1u)) >> 16);
}
__device__ __forceinline__ float bf2f(unsigned short b) {
    union { unsigned u; float f; } v; v.u = ((unsigned)b) << 16;
    return v.f;
}

// ---------------- Kernel 1: per-chunk state sums via MFMA (R10, verified) ----
__global__ __launch_bounds__(256) void chunksum_kernel(
    const float* __restrict__ Kin, const float* __restrict__ Vin,
    unsigned short* __restrict__ ws)
{
    __shared__ __align__(16) unsigned short K1T[EE][SB];  // [e][j]
    __shared__ __align__(16) unsigned short K2T[EE][SB];  // [e][j]
    __shared__ __align__(16) unsigned short VT [EE][SB];  // [d][j]

    const int b  = blockIdx.x;
    const int c  = b & (NCH - 1);
    const int nh = b >> 6;
    const int t  = threadIdx.x;
    const int lane = t & 31;
    const int grp  = t >> 5;    // 0..7

    for (int r = grp; r < CC; r += 8) {
        const int l = c * CC + r;
        const int base = ((nh >> 3) * LL + l) * HH * EE + (nh & 7) * EE + lane;
        const float k = Kin[base];
        const float v = Vin[base];
        const float f1 = elu1(k);
        const float f2 = f1 * f1;
        float s1 = f1, s2 = f2;
        #pragma unroll
        for (int m = 1; m < 32; m <<= 1) {
            s1 += __shfl_xor(s1, m, 32);
            s2 += __shfl_xor(s2, m, 32);
        }
        K1T[lane][r] = bfr(f1 * __builtin_amdgcn_rcpf(s1));   // s1,s2 > 0
        K2T[lane][r] = bfr(f2 * __builtin_amdgcn_rcpf(s2));
        VT [lane][r] = bfr(v);
    }
    __syncthreads();

    const int wid = t >> 6;         // 0..3
    const int l64 = t & 63;
    const int l31 = l64 & 31;       // A-row (=d) / C-col (=e)
    const int hi5 = l64 >> 5;       // k-half selector

    if (wid < 2) {                  // wave 0: branch 1, wave 1: branch 2
        const unsigned short* KT = wid ? &K2T[0][0] : &K1T[0][0];
        const s16x8 va0 = *(const s16x8*)&VT[l31][8 * hi5];
        const s16x8 va1 = *(const s16x8*)&VT[l31][16 + 8 * hi5];
        const s16x8 kb0 = *(const s16x8*)&KT[l31 * SB + 8 * hi5];
        const s16x8 kb1 = *(const s16x8*)&KT[l31 * SB + 16 + 8 * hi5];
        s16x8 ones;
        #pragma unroll
        for (int i = 0; i < 8; ++i) ones[i] = (short)0x3F80;  // bf16 1.0

        f32x16 S = {};
        S = __builtin_amdgcn_mfma_f32_32x32x16_bf16(va0, kb0, S, 0, 0, 0);
        S = __builtin_amdgcn_mfma_f32_32x32x16_bf16(va1, kb1, S, 0, 0, 0);
        f32x16 Dk = {};
        Dk = __builtin_amdgcn_mfma_f32_32x32x16_bf16(ones, kb0, Dk, 0, 0, 0);
        Dk = __builtin_amdgcn_mfma_f32_32x32x16_bf16(ones, kb1, Dk, 0, 0, 0);

        unsigned short* wb = ws + (size_t)b * REC + (wid ? OFF_S2 : OFF_S1);
        unsigned short* wk = ws + (size_t)b * REC + (wid ? OFF_K2 : OFF_K1);
        #pragma unroll
        for (int k = 0; k < 16; ++k) {
            const int row = (k & 3) + 8 * (k >> 2) + 4 * hi5;   // = d
            wb[row * EE + l31] = bfr(S[k]);
        }
        if (hi5 == 0) wk[l31] = bfr(Dk[0]);   // ks[e]
    }
}

// ---------------- Kernel 2: exclusive prefix over chunks (bf16, f32 carry) --
__global__ __launch_bounds__(192) void prefix_kernel(unsigned short* __restrict__ ws)
{
    const int g = blockIdx.x / 11;
    const int e = (blockIdx.x % 11) * 192 + threadIdx.x;   // 0..2111
    unsigned short* base = ws + (size_t)g * NCH * REC + e;
    float run = 0.f;
    {
        unsigned short v[32];
        #pragma unroll
        for (int c = 0; c < 32; ++c) v[c] = base[(size_t)c * REC];
        #pragma unroll
        for (int c = 0; c < 32; ++c) {
            base[(size_t)c * REC] = bfr(run);
            run += bf2f(v[c]);
        }
    }
    {
        unsigned short v[32];
        #pragma unroll
        for (int c = 0; c < 32; ++c) v[c] = base[(size_t)(32 + c) * REC];
        #pragma unroll
        for (int c = 0; c < 32; ++c) {
            base[(size_t)(32 + c) * REC] = bfr(run);
            run += bf2f(v[c]);
        }
    }
}

// ---------------- Kernel 3: all-MFMA fused (band on wave 1, linear 0/2) -----
// Band: S^T = Krb x Qrb^T (C/D col=lane=q -> softmax stats are LANE-SCALARS,
// 2 shfl_xor(32) total), mask+exp+1/den in-reg, relayout to Pband, PV = 3
// MFMA vs Vtb. WINDOW PARTITION (R12 fix): lo window owns jk<=8 ONLY, hi
// window (jh=jl+9) owns jk>=9 — overlap jk in [9,31] was double-counted in
// den in the R11 draft (never run). Waves 0/2 run linear concurrently.
__global__ __launch_bounds__(256) void fused_kernel(
    const float* __restrict__ Qin, const float* __restrict__ Kin,
    const float* __restrict__ Vin,
    const float* __restrict__ W1, const float* __restrict__ W2,
    const float* __restrict__ W3, const unsigned short* __restrict__ ws,
    float* __restrict__ out)
{
    __shared__ __align__(16) unsigned short Qfb[CC][SB];   // bf16 elu1(Q)
    __shared__ __align__(16) unsigned short Kfb[CC][SB];   // bf16 elu1(K)
    __shared__ __align__(16) unsigned short Qrb[CC][SB];   // bf16 Q*temp (band)
    __shared__ __align__(16) unsigned short Krb[41][SB];   // bf16 raw K rows l0-9..l0+31
    __shared__ __align__(16) unsigned short Vtb[EE][VS];   // bf16 V^T: cols 0..31 chunk, 32..40 prev, 41..47 zero
    __shared__ __align__(16) unsigned short Pb1[CC][SB];   // P relayout (branch 1)
    __shared__ __align__(16) unsigned short Pb2[CC][SB];   // P relayout (branch 2)
    __shared__ __align__(16) unsigned short Pbd[CC][VS];   // band P relayout
    __shared__ __align__(16) unsigned short Obb[CC][SB];   // band output bf16 (small vals)
    __shared__ float Ob1[CC][SK];          // branch outputs f32 (w*z applied)
    __shared__ float Ob2[CC][SK];
    __shared__ __align__(16) unsigned short sp[REC];       // prefix record

    const int b  = blockIdx.x;
    const int c  = b & (NCH - 1);
    const int nh = b >> 6;
    const int h  = nh & 7;
    const int n  = nh >> 3;
    const int l0 = c * CC;
    const int t  = threadIdx.x;
    const int lane = t & 31;
    const int grp  = t >> 5;       // 0..7

    // own exclusive-prefix record -> registers early
    const uint4* wbv = (const uint4*)(ws + (size_t)b * REC);
    const uint4 s0 = wbv[t];
    uint4 s1 = {0u, 0u, 0u, 0u};
    if (t < R16 - 256) s1 = wbv[256 + t];          // last 8

    // ---------------- Phase A: pure staging (no reductions) -----------------
    const float temp = 0.17677669529663687f;   // 1/sqrt(32), folded into Qrb
    for (int r = grp; r < CC; r += 8) {
        const int l = l0 + r;
        const int base = ((n * LL + l) * HH + h) * EE + lane;
        const float k = Kin[base];
        const float v = Vin[base];
        const float q = Qin[base];
        Kfb[r][lane] = bfr(elu1(k));
        Qfb[r][lane] = bfr(elu1(q));
        Qrb[r][lane] = bfr(q * temp);
        Krb[9 + r][lane] = bfr(k);
        Vtb[lane][r] = bfr(v);
    }
    // previous 9 rows of raw K,V (zero-padded at sequence start)
    for (int idx = t; idx < 9 * 32; idx += 256) {
        const int rr = idx >> 5, ln = idx & 31;
        const int l = l0 - 9 + rr;
        float kv = 0.f, vv = 0.f;
        if (l >= 0) {
            const int gbase = ((n * LL + l) * HH + h) * EE + ln;
            kv = Kin[gbase];
            vv = Vin[gbase];
        }
        Krb[rr][ln] = bfr(kv);
        Vtb[ln][32 + rr] = bfr(vv);
    }
    // zero Vtb pad cols 41..47 (garbage here would poison the W1 PV mfma)
    if (t < 32) {
        #pragma unroll
        for (int cc = 41; cc < 48; ++cc) Vtb[t][cc] = 0;
    }
    // publish prefix record
    ((uint4*)sp)[t] = s0;
    if (t < R16 - 256) ((uint4*)sp)[256 + t] = s1;
    __syncthreads();

    const int wid = t >> 6;
    const int l64 = t & 63;
    const int l31 = l64 & 31;
    const int hi5 = l64 >> 5;

    if ((wid & 1) == 0) {
        // ------------- linear branches via MFMA (R10-verified chain) --------
        const bool b2 = (wid == 2);
        const unsigned short* Spt = sp + (b2 ? OFF_S2 : OFF_S1); // St[d][e]
        const unsigned short* kp  = sp + (b2 ? OFF_K2 : OFF_K1);
        const float* Wv = b2 ? W3 : W2;
        unsigned short* Pb = b2 ? &Pb2[0][0] : &Pb1[0][0];
        float* Ob = b2 ? &Ob2[0][0] : &Ob1[0][0];

        s16x8 qa0 = *(const s16x8*)&Qfb[l31][8 * hi5];
        s16x8 qa1 = *(const s16x8*)&Qfb[l31][16 + 8 * hi5];
        s16x8 kb0 = *(const s16x8*)&Kfb[l31][8 * hi5];
        s16x8 kb1 = *(const s16x8*)&Kfb[l31][16 + 8 * hi5];
        if (b2) {
            #pragma unroll
            for (int i = 0; i < 8; ++i) {
                float f;
                f = bf2f((unsigned short)qa0[i]); qa0[i] = (short)bfr(f * f);
                f = bf2f((unsigned short)qa1[i]); qa1[i] = (short)bfr(f * f);
                f = bf2f((unsigned short)kb0[i]); kb0[i] = (short)bfr(f * f);
                f = bf2f((unsigned short)kb1[i]); kb1[i] = (short)bfr(f * f);
            }
        }
        s16x8 ones;
        #pragma unroll
        for (int i = 0; i < 8; ++i) ones[i] = (short)0x3F80;  // bf16 1.0

        f32x16 Dk = {};
        Dk = __builtin_amdgcn_mfma_f32_32x32x16_bf16(ones, kb0, Dk, 0, 0, 0);
        Dk = __builtin_amdgcn_mfma_f32_32x32x16_bf16(ones, kb1, Dk, 0, 0, 0);
        f32x16 P = {};
        P = __builtin_amdgcn_mfma_f32_32x32x16_bf16(qa0, kb0, P, 0, 0, 0);
        P = __builtin_amdgcn_mfma_f32_32x32x16_bf16(qa1, kb1, P, 0, 0, 0);

        const float ki = __builtin_amdgcn_rcpf(Dk[0]);   // 1/sk[l31]
        #pragma unroll
        for (int k = 0; k < 16; ++k) {
            const int row = (k & 3) + 8 * (k >> 2) + 4 * hi5;
            Pb[row * SB + l31] = bfr((l31 <= row) ? P[k] * ki : 0.f);
        }
        const s16x8 pa0 = *(const s16x8*)&Pb[l31 * SB + 8 * hi5];
        const s16x8 pa1 = *(const s16x8*)&Pb[l31 * SB + 16 + 8 * hi5];

        const s16x8 vb0 = *(const s16x8*)&Vtb[l31][8 * hi5];
        const s16x8 vb1 = *(const s16x8*)&Vtb[l31][16 + 8 * hi5];
        const s16x8 sb0 = *(const s16x8*)&Spt[l31 * EE + 8 * hi5];
        const s16x8 sb1 = *(const s16x8*)&Spt[l31 * EE + 16 + 8 * hi5];
        const s16x8 rb0 = *(const s16x8*)&kp[8 * hi5];
        const s16x8 rb1 = *(const s16x8*)&kp[16 + 8 * hi5];

        f32x16 A = {};
        A = __builtin_amdgcn_mfma_f32_32x32x16_bf16(pa0, vb0, A, 0, 0, 0);
        A = __builtin_amdgcn_mfma_f32_32x32x16_bf16(pa1, vb1, A, 0, 0, 0);
        A = __builtin_amdgcn_mfma_f32_32x32x16_bf16(qa0, sb0, A, 0, 0, 0);
        A = __builtin_amdgcn_mfma_f32_32x32x16_bf16(qa1, sb1, A, 0, 0, 0);

        f32x16 Dp = {};
        Dp = __builtin_amdgcn_mfma_f32_32x32x16_bf16(pa0, ones, Dp, 0, 0, 0);
        Dp = __builtin_amdgcn_mfma_f32_32x32x16_bf16(pa1, ones, Dp, 0, 0, 0);
        Dp = __builtin_amdgcn_mfma_f32_32x32x16_bf16(qa0, rb0, Dp, 0, 0, 0);
        Dp = __builtin_amdgcn_mfma_f32_32x32x16_bf16(qa1, rb1, Dp, 0, 0, 0);

        const float wv = Wv[h * EE + l31];
        #pragma unroll
        for (int k = 0; k < 16; ++k) {
            const int row = (k & 3) + 8 * (k >> 2) + 4 * hi5;
            Ob[row * SK + l31] = wv * A[k] * __builtin_amdgcn_rcpf(Dp[k]);
        }
    } else if (wid == 1) {
        // ------------- band via MFMA (transposed scores) --------------------
        const int q = l31;                         // query row (= C/D col)
        const int jmin = (l0 >= 9) ? 0 : 9 - l0;   // first valid Krb index
        // B-frags: Qrb row q (temp pre-folded)
        const s16x8 qb0 = *(const s16x8*)&Qrb[q][8 * hi5];
        const s16x8 qb1 = *(const s16x8*)&Qrb[q][16 + 8 * hi5];
        // A-frags: Krb rows j (lo window 0..31) and 9+j (hi window 9..40)
        const s16x8 kl0 = *(const s16x8*)&Krb[l31][8 * hi5];
        const s16x8 kl1 = *(const s16x8*)&Krb[l31][16 + 8 * hi5];
        const s16x8 kh0 = *(const s16x8*)&Krb[9 + l31][8 * hi5];
        const s16x8 kh1 = *(const s16x8*)&Krb[9 + l31][16 + 8 * hi5];

        f32x16 Slo = {}, Shi = {};
        Slo = __builtin_amdgcn_mfma_f32_32x32x16_bf16(kl0, qb0, Slo, 0, 0, 0);
        Slo = __builtin_amdgcn_mfma_f32_32x32x16_bf16(kl1, qb1, Slo, 0, 0, 0);
        Shi = __builtin_amdgcn_mfma_f32_32x32x16_bf16(kh0, qb0, Shi, 0, 0, 0);
        Shi = __builtin_amdgcn_mfma_f32_32x32x16_bf16(kh1, qb1, Shi, 0, 0, 0);

        // PARTITION: lo window owns jk<=8 only; hi window owns jk>=9.
        // band membership: q <= jk <= q+9, jk >= jmin.
        float m = -INFINITY;
        #pragma unroll
        for (int k = 0; k < 16; ++k) {
            const int jl = (k & 3) + 8 * (k >> 2) + 4 * hi5;
            const int jh = jl + 9;
            if (jl <= 8 && jl >= q && jl >= jmin) m = fmaxf(m, Slo[k]);  // jl<=8<q+9
            if (jh >= q && jh <= q + 9) m = fmaxf(m, Shi[k]);            // jh>=9>=jmin
        }
        m = fmaxf(m, __shfl_xor(m, 32, 64));       // combine hi5 halves
        float den = 0.f;
        float plo[16], phi[16];
        #pragma unroll
        for (int k = 0; k < 16; ++k) {
            const int jl = (k & 3) + 8 * (k >> 2) + 4 * hi5;
            const int jh = jl + 9;
            plo[k] = __expf(Slo[k] - m);
            phi[k] = __expf(Shi[k] - m);
            if (jl <= 8 && jl >= q && jl >= jmin) den += plo[k];
            if (jh >= q && jh <= q + 9) den += phi[k];
        }
        den += __shfl_xor(den, 32, 64);
        const float inv = __builtin_amdgcn_rcpf(den);

        // zero own P row (halves split cols 0..23 / 24..47), then scatter
        {
            const uint4 z = {0u, 0u, 0u, 0u};
            *(uint4*)&Pbd[q][24 * hi5 + 0]  = z;
            *(uint4*)&Pbd[q][24 * hi5 + 8]  = z;
            *(uint4*)&Pbd[q][24 * hi5 + 16] = z;
        }
        #pragma unroll
        for (int k = 0; k < 16; ++k) {
            const int jl = (k & 3) + 8 * (k >> 2) + 4 * hi5;
            const int jh = jl + 9;
            // lo entries are jk<9 -> prev window col 32+jk
            if (jl <= 8 && jl >= q && jl >= jmin)
                Pbd[q][32 + jl] = bfr(plo[k] * inv);
            // hi entries jk=jh>=9 -> chunk col jh-9
            if (jh >= q && jh <= q + 9)
                Pbd[q][jh - 9] = bfr(phi[k] * inv);
        }

        // PV: cols 0..31 (chunk) K=32, cols 32..47 (prev+zero pad) K=16
        const s16x8 pa0 = *(const s16x8*)&Pbd[l31][8 * hi5];
        const s16x8 pa1 = *(const s16x8*)&Pbd[l31][16 + 8 * hi5];
        const s16x8 pa2 = *(const s16x8*)&Pbd[l31][32 + 8 * hi5];
        const s16x8 vb0 = *(const s16x8*)&Vtb[l31][8 * hi5];
        const s16x8 vb1 = *(const s16x8*)&Vtb[l31][16 + 8 * hi5];
        const s16x8 vb2 = *(const s16x8*)&Vtb[l31][32 + 8 * hi5];
        f32x16 OB = {};
        OB = __builtin_amdgcn_mfma_f32_32x32x16_bf16(pa0, vb0, OB, 0, 0, 0);
        OB = __builtin_amdgcn_mfma_f32_32x32x16_bf16(pa1, vb1, OB, 0, 0, 0);
        OB = __builtin_amdgcn_mfma_f32_32x32x16_bf16(pa2, vb2, OB, 0, 0, 0);

        const float w1v = W1[h * EE + l31];        // C/D col = lane = d
        #pragma unroll
        for (int k = 0; k < 16; ++k) {
            const int row = (k & 3) + 8 * (k >> 2) + 4 * hi5;  // = q
            Obb[row][l31] = bfr(w1v * OB[k]);
        }
    }
    __syncthreads();

    // ---------------- final combine + single store (cluster mapping) --------
    const int r   = t >> 3;
    const int d0  = (t & 7) * 4;
    const int l   = l0 + r;
    const float4 o1 = *(const float4*)&Ob1[r][d0];
    const float4 o2 = *(const float4*)&Ob2[r][d0];
    const ushort4 ob = *(const ushort4*)&Obb[r][d0];
    float4 o;
    o.x = bf2f(ob.x) + o1.x + o2.x;
    o.y = bf2f(ob.y) + o1.y + o2.y;
    o.z = bf2f(ob.z) + o1.z + o2.z;
    o.w = bf2f(ob.w) + o1.w + o2.w;
    *(float4*)&out[((n * LL + l) * HH + h) * EE + d0] = o;
}

extern "C" void kernel_launch(void* const* d_in, const int* in_sizes, int n_in,
                              void* d_out, int out_size, void* d_ws, size_t ws_size,
                              hipStream_t stream)
{
    (void)in_sizes; (void)n_in; (void)out_size; (void)ws_size;
    const float* Q  = (const float*)d_in[0];
    const float* K  = (const float*)d_in[1];
    const float* V  = (const float*)d_in[2];
    // d_in[3] = key_lengths: cancels mathematically (normalization over E)
    const float* W1 = (const float*)d_in[4];
    const float* W2 = (const float*)d_in[5];
    const float* W3 = (const float*)d_in[6];
    float* out = (float*)d_out;
    unsigned short* ws = (unsigned short*)d_ws;   // NB*REC*2 = ~4.3 MB scratch

    chunksum_kernel<<<NB,           256, 0, stream>>>(K, V, ws);
    prefix_kernel  <<<NN * HH * 11, 192, 0, stream>>>(ws);
    fused_kernel   <<<NB,           256, 0, stream>>>(Q, K, V, W1, W2, W3, ws, out);
}

// Round 13
// 87.500 us; speedup vs baseline: 1.3101x; 1.0025x over previous
//
#include <hip/hip_runtime.h>
#include <cmath>

// Problem constants (fixed by setup_inputs)
constexpr int NN = 2;       // batch
constexpr int LL = 2048;    // sequence
constexpr int HH = 8;       // heads
constexpr int EE = 32;      // feature dim == value dim
constexpr int CC = 32;      // chunk length
constexpr int NCH = LL / CC;       // 64 chunks per (n,h)
constexpr int NB  = NN * HH * NCH; // 1024 blocks
constexpr int BWD = 10;     // softmax bandwidth
// bf16 record per chunk (shorts): St1[d][e] 32x32, k1[32], St2, k2
constexpr int REC  = 2 * (EE * EE + EE);   // 2112 shorts = 4224 B
constexpr int R16  = REC * 2 / 16;         // 264 16-byte slots
constexpr int OFF_S1 = 0, OFF_K1 = 1024, OFF_S2 = 1056, OFF_K2 = 2080; // short idx
constexpr int SK = EE + 4;   // 36: float4-aligned f32 row stride (144 B)
constexpr int SB = 40;       // bf16 LDS row stride (80 B, 16B-aligned rows)
constexpr int VS = 48;       // Vtb/Pband col count (96 B rows, 16B-aligned)

using f32x16 = __attribute__((ext_vector_type(16))) float;
using s16x8  = __attribute__((ext_vector_type(8)))  short;

__device__ __forceinline__ float elu1(float x) {
    return x > 0.f ? x + 1.f : __expf(x);   // elu(x)+1
}
// f32 -> bf16 bits, round-to-nearest-even (inputs finite)
__device__ __forceinline__ unsigned short bfr(float x) {
    union { float f; unsigned u; } v; v.f = x;
    return (unsigned short)((v.u + 0x7FFFu + ((v.u >> 16) & 1u)) >> 16);
}
__device__ __forceinline__ float bf2f(unsigned short b) {
    union { unsigned u; float f; } v; v.u = ((unsigned)b) << 16;
    return v.f;
}

// ---------------- Kernel 1: per-chunk state sums via MFMA (R10, verified) ----
__global__ __launch_bounds__(256) void chunksum_kernel(
    const float* __restrict__ Kin, const float* __restrict__ Vin,
    unsigned short* __restrict__ ws)
{
    __shared__ __align__(16) unsigned short K1T[EE][SB];  // [e][j]
    __shared__ __align__(16) unsigned short K2T[EE][SB];  // [e][j]
    __shared__ __align__(16) unsigned short VT [EE][SB];  // [d][j]

    const int b  = blockIdx.x;
    const int c  = b & (NCH - 1);
    const int nh = b >> 6;
    const int t  = threadIdx.x;
    const int lane = t & 31;
    const int grp  = t >> 5;    // 0..7

    for (int r = grp; r < CC; r += 8) {
        const int l = c * CC + r;
        const int base = ((nh >> 3) * LL + l) * HH * EE + (nh & 7) * EE + lane;
        const float k = Kin[base];
        const float v = Vin[base];
        const float f1 = elu1(k);
        const float f2 = f1 * f1;
        float s1 = f1, s2 = f2;
        #pragma unroll
        for (int m = 1; m < 32; m <<= 1) {
            s1 += __shfl_xor(s1, m, 32);
            s2 += __shfl_xor(s2, m, 32);
        }
        K1T[lane][r] = bfr(f1 * __builtin_amdgcn_rcpf(s1));   // s1,s2 > 0
        K2T[lane][r] = bfr(f2 * __builtin_amdgcn_rcpf(s2));
        VT [lane][r] = bfr(v);
    }
    __syncthreads();

    const int wid = t >> 6;         // 0..3
    const int l64 = t & 63;
    const int l31 = l64 & 31;       // A-row (=d) / C-col (=e)
    const int hi5 = l64 >> 5;       // k-half selector

    if (wid < 2) {                  // wave 0: branch 1, wave 1: branch 2
        const unsigned short* KT = wid ? &K2T[0][0] : &K1T[0][0];
        const s16x8 va0 = *(const s16x8*)&VT[l31][8 * hi5];
        const s16x8 va1 = *(const s16x8*)&VT[l31][16 + 8 * hi5];
        const s16x8 kb0 = *(const s16x8*)&KT[l31 * SB + 8 * hi5];
        const s16x8 kb1 = *(const s16x8*)&KT[l31 * SB + 16 + 8 * hi5];
        s16x8 ones;
        #pragma unroll
        for (int i = 0; i < 8; ++i) ones[i] = (short)0x3F80;  // bf16 1.0

        f32x16 S = {};
        S = __builtin_amdgcn_mfma_f32_32x32x16_bf16(va0, kb0, S, 0, 0, 0);
        S = __builtin_amdgcn_mfma_f32_32x32x16_bf16(va1, kb1, S, 0, 0, 0);
        f32x16 Dk = {};
        Dk = __builtin_amdgcn_mfma_f32_32x32x16_bf16(ones, kb0, Dk, 0, 0, 0);
        Dk = __builtin_amdgcn_mfma_f32_32x32x16_bf16(ones, kb1, Dk, 0, 0, 0);

        unsigned short* wb = ws + (size_t)b * REC + (wid ? OFF_S2 : OFF_S1);
        unsigned short* wk = ws + (size_t)b * REC + (wid ? OFF_K2 : OFF_K1);
        #pragma unroll
        for (int k = 0; k < 16; ++k) {
            const int row = (k & 3) + 8 * (k >> 2) + 4 * hi5;   // = d
            wb[row * EE + l31] = bfr(S[k]);
        }
        if (hi5 == 0) wk[l31] = bfr(Dk[0]);   // ks[e]
    }
}

// ---------------- Kernel 2: exclusive prefix over chunks (bf16, f32 carry) --
__global__ __launch_bounds__(192) void prefix_kernel(unsigned short* __restrict__ ws)
{
    const int g = blockIdx.x / 11;
    const int e = (blockIdx.x % 11) * 192 + threadIdx.x;   // 0..2111
    unsigned short* base = ws + (size_t)g * NCH * REC + e;
    float run = 0.f;
    {
        unsigned short v[32];
        #pragma unroll
        for (int c = 0; c < 32; ++c) v[c] = base[(size_t)c * REC];
        #pragma unroll
        for (int c = 0; c < 32; ++c) {
            base[(size_t)c * REC] = bfr(run);
            run += bf2f(v[c]);
        }
    }
    {
        unsigned short v[32];
        #pragma unroll
        for (int c = 0; c < 32; ++c) v[c] = base[(size_t)(32 + c) * REC];
        #pragma unroll
        for (int c = 0; c < 32; ++c) {
            base[(size_t)(32 + c) * REC] = bfr(run);
            run += bf2f(v[c]);
        }
    }
}

// ---------------- Kernel 3: all-MFMA fused -----------------------------------
// R13: (1) vectorized Phase-A staging: thread=(row, col-quad), float4 global
// loads + b64 LDS writes (was 20 scalar b16 writes + 12 scalar loads);
// (2) prefix-record LDS round-trip DELETED — linear waves load S/k fragments
// directly from global ws (L2-hot, 16B dwordx4, hidden under Dk/P MFMAs).
// Band (wave 1) + linear (waves 0/2) MFMA phases unchanged from R12.
__global__ __launch_bounds__(256) void fused_kernel(
    const float* __restrict__ Qin, const float* __restrict__ Kin,
    const float* __restrict__ Vin,
    const float* __restrict__ W1, const float* __restrict__ W2,
    const float* __restrict__ W3, const unsigned short* __restrict__ ws,
    float* __restrict__ out)
{
    __shared__ __align__(16) unsigned short Qfb[CC][SB];   // bf16 elu1(Q)
    __shared__ __align__(16) unsigned short Kfb[CC][SB];   // bf16 elu1(K)
    __shared__ __align__(16) unsigned short Qrb[CC][SB];   // bf16 Q*temp (band)
    __shared__ __align__(16) unsigned short Krb[41][SB];   // bf16 raw K rows l0-9..l0+31
    __shared__ __align__(16) unsigned short Vtb[EE][VS];   // bf16 V^T: cols 0..31 chunk, 32..40 prev, 41..47 zero
    __shared__ __align__(16) unsigned short Pb1[CC][SB];   // P relayout (branch 1)
    __shared__ __align__(16) unsigned short Pb2[CC][SB];   // P relayout (branch 2)
    __shared__ __align__(16) unsigned short Pbd[CC][VS];   // band P relayout
    __shared__ __align__(16) unsigned short Obb[CC][SB];   // band output bf16
    __shared__ float Ob1[CC][SK];          // branch outputs f32 (w*z applied)
    __shared__ float Ob2[CC][SK];

    const int b  = blockIdx.x;
    const int c  = b & (NCH - 1);
    const int nh = b >> 6;
    const int h  = nh & 7;
    const int n  = nh >> 3;
    const int l0 = c * CC;
    const int t  = threadIdx.x;

    // ---------------- Phase A: vectorized staging ---------------------------
    const float temp = 0.17677669529663687f;   // 1/sqrt(32), folded into Qrb
    const int r   = t >> 3;        // row 0..31
    const int sub = t & 7;
    const int d0  = sub * 4;       // col quad
    const int l   = l0 + r;
    {
        const int base = ((n * LL + l) * HH + h) * EE + d0;
        const float4 k4 = *(const float4*)&Kin[base];
        const float4 v4 = *(const float4*)&Vin[base];
        const float4 q4 = *(const float4*)&Qin[base];
        ushort4 kf = { bfr(elu1(k4.x)), bfr(elu1(k4.y)), bfr(elu1(k4.z)), bfr(elu1(k4.w)) };
        ushort4 qf = { bfr(elu1(q4.x)), bfr(elu1(q4.y)), bfr(elu1(q4.z)), bfr(elu1(q4.w)) };
        ushort4 qr = { bfr(q4.x * temp), bfr(q4.y * temp), bfr(q4.z * temp), bfr(q4.w * temp) };
        ushort4 kr = { bfr(k4.x), bfr(k4.y), bfr(k4.z), bfr(k4.w) };
        *(ushort4*)&Kfb[r][d0] = kf;
        *(ushort4*)&Qfb[r][d0] = qf;
        *(ushort4*)&Qrb[r][d0] = qr;
        *(ushort4*)&Krb[9 + r][d0] = kr;
        Vtb[d0 + 0][r] = bfr(v4.x);
        Vtb[d0 + 1][r] = bfr(v4.y);
        Vtb[d0 + 2][r] = bfr(v4.z);
        Vtb[d0 + 3][r] = bfr(v4.w);
    }
    // previous 9 rows of raw K,V (zero-padded at sequence start)
    if (t < 72) {
        const int rr = t >> 3, dd0 = (t & 7) * 4;
        const int lp = l0 - 9 + rr;
        float4 k4 = {0.f, 0.f, 0.f, 0.f};
        float4 v4 = {0.f, 0.f, 0.f, 0.f};
        if (lp >= 0) {
            const int gbase = ((n * LL + lp) * HH + h) * EE + dd0;
            k4 = *(const float4*)&Kin[gbase];
            v4 = *(const float4*)&Vin[gbase];
        }
        ushort4 kr = { bfr(k4.x), bfr(k4.y), bfr(k4.z), bfr(k4.w) };
        *(ushort4*)&Krb[rr][dd0] = kr;
        Vtb[dd0 + 0][32 + rr] = bfr(v4.x);
        Vtb[dd0 + 1][32 + rr] = bfr(v4.y);
        Vtb[dd0 + 2][32 + rr] = bfr(v4.z);
        Vtb[dd0 + 3][32 + rr] = bfr(v4.w);
    }
    // zero Vtb pad cols 41..47 (garbage here would poison the W1 PV mfma)
    if (t < 32) {
        #pragma unroll
        for (int cc = 41; cc < 48; ++cc) Vtb[t][cc] = 0;
    }
    __syncthreads();

    const int wid = t >> 6;
    const int l64 = t & 63;
    const int l31 = l64 & 31;
    const int hi5 = l64 >> 5;

    if ((wid & 1) == 0) {
        // ------------- linear branches via MFMA (R10-verified chain) --------
        const bool b2 = (wid == 2);
        // S/k fragments DIRECT from global ws (L2-hot exclusive-prefix record)
        const unsigned short* SptG = ws + (size_t)b * REC + (b2 ? OFF_S2 : OFF_S1);
        const unsigned short* kpG  = ws + (size_t)b * REC + (b2 ? OFF_K2 : OFF_K1);
        const float* Wv = b2 ? W3 : W2;
        unsigned short* Pb = b2 ? &Pb2[0][0] : &Pb1[0][0];
        float* Ob = b2 ? &Ob2[0][0] : &Ob1[0][0];

        const s16x8 sb0 = *(const s16x8*)&SptG[l31 * EE + 8 * hi5];   // 16B global
        const s16x8 sb1 = *(const s16x8*)&SptG[l31 * EE + 16 + 8 * hi5];
        const s16x8 rb0 = *(const s16x8*)&kpG[8 * hi5];
        const s16x8 rb1 = *(const s16x8*)&kpG[16 + 8 * hi5];

        s16x8 qa0 = *(const s16x8*)&Qfb[l31][8 * hi5];
        s16x8 qa1 = *(const s16x8*)&Qfb[l31][16 + 8 * hi5];
        s16x8 kb0 = *(const s16x8*)&Kfb[l31][8 * hi5];
        s16x8 kb1 = *(const s16x8*)&Kfb[l31][16 + 8 * hi5];
        if (b2) {
            #pragma unroll
            for (int i = 0; i < 8; ++i) {
                float f;
                f = bf2f((unsigned short)qa0[i]); qa0[i] = (short)bfr(f * f);
                f = bf2f((unsigned short)qa1[i]); qa1[i] = (short)bfr(f * f);
                f = bf2f((unsigned short)kb0[i]); kb0[i] = (short)bfr(f * f);
                f = bf2f((unsigned short)kb1[i]); kb1[i] = (short)bfr(f * f);
            }
        }
        s16x8 ones;
        #pragma unroll
        for (int i = 0; i < 8; ++i) ones[i] = (short)0x3F80;  // bf16 1.0

        f32x16 Dk = {};
        Dk = __builtin_amdgcn_mfma_f32_32x32x16_bf16(ones, kb0, Dk, 0, 0, 0);
        Dk = __builtin_amdgcn_mfma_f32_32x32x16_bf16(ones, kb1, Dk, 0, 0, 0);
        f32x16 P = {};
        P = __builtin_amdgcn_mfma_f32_32x32x16_bf16(qa0, kb0, P, 0, 0, 0);
        P = __builtin_amdgcn_mfma_f32_32x32x16_bf16(qa1, kb1, P, 0, 0, 0);

        const float ki = __builtin_amdgcn_rcpf(Dk[0]);   // 1/sk[l31]
        #pragma unroll
        for (int k = 0; k < 16; ++k) {
            const int row = (k & 3) + 8 * (k >> 2) + 4 * hi5;
            Pb[row * SB + l31] = bfr((l31 <= row) ? P[k] * ki : 0.f);
        }
        const s16x8 pa0 = *(const s16x8*)&Pb[l31 * SB + 8 * hi5];
        const s16x8 pa1 = *(const s16x8*)&Pb[l31 * SB + 16 + 8 * hi5];

        const s16x8 vb0 = *(const s16x8*)&Vtb[l31][8 * hi5];
        const s16x8 vb1 = *(const s16x8*)&Vtb[l31][16 + 8 * hi5];

        f32x16 A = {};
        A = __builtin_amdgcn_mfma_f32_32x32x16_bf16(pa0, vb0, A, 0, 0, 0);
        A = __builtin_amdgcn_mfma_f32_32x32x16_bf16(pa1, vb1, A, 0, 0, 0);
        A = __builtin_amdgcn_mfma_f32_32x32x16_bf16(qa0, sb0, A, 0, 0, 0);
        A = __builtin_amdgcn_mfma_f32_32x32x16_bf16(qa1, sb1, A, 0, 0, 0);

        f32x16 Dp = {};
        Dp = __builtin_amdgcn_mfma_f32_32x32x16_bf16(pa0, ones, Dp, 0, 0, 0);
        Dp = __builtin_amdgcn_mfma_f32_32x32x16_bf16(pa1, ones, Dp, 0, 0, 0);
        Dp = __builtin_amdgcn_mfma_f32_32x32x16_bf16(qa0, rb0, Dp, 0, 0, 0);
        Dp = __builtin_amdgcn_mfma_f32_32x32x16_bf16(qa1, rb1, Dp, 0, 0, 0);

        const float wv = Wv[h * EE + l31];
        #pragma unroll
        for (int k = 0; k < 16; ++k) {
            const int row = (k & 3) + 8 * (k >> 2) + 4 * hi5;
            Ob[row * SK + l31] = wv * A[k] * __builtin_amdgcn_rcpf(Dp[k]);
        }
    } else if (wid == 1) {
        // ------------- band via MFMA (R12-verified, partitioned windows) ----
        const int q = l31;                         // query row (= C/D col)
        const int jmin = (l0 >= 9) ? 0 : 9 - l0;   // first valid Krb index
        const s16x8 qb0 = *(const s16x8*)&Qrb[q][8 * hi5];
        const s16x8 qb1 = *(const s16x8*)&Qrb[q][16 + 8 * hi5];
        const s16x8 kl0 = *(const s16x8*)&Krb[l31][8 * hi5];
        const s16x8 kl1 = *(const s16x8*)&Krb[l31][16 + 8 * hi5];
        const s16x8 kh0 = *(const s16x8*)&Krb[9 + l31][8 * hi5];
        const s16x8 kh1 = *(const s16x8*)&Krb[9 + l31][16 + 8 * hi5];

        f32x16 Slo = {}, Shi = {};
        Slo = __builtin_amdgcn_mfma_f32_32x32x16_bf16(kl0, qb0, Slo, 0, 0, 0);
        Slo = __builtin_amdgcn_mfma_f32_32x32x16_bf16(kl1, qb1, Slo, 0, 0, 0);
        Shi = __builtin_amdgcn_mfma_f32_32x32x16_bf16(kh0, qb0, Shi, 0, 0, 0);
        Shi = __builtin_amdgcn_mfma_f32_32x32x16_bf16(kh1, qb1, Shi, 0, 0, 0);

        // PARTITION: lo window owns jk<=8 only; hi window owns jk>=9.
        float m = -INFINITY;
        #pragma unroll
        for (int k = 0; k < 16; ++k) {
            const int jl = (k & 3) + 8 * (k >> 2) + 4 * hi5;
            const int jh = jl + 9;
            if (jl <= 8 && jl >= q && jl >= jmin) m = fmaxf(m, Slo[k]);
            if (jh >= q && jh <= q + 9) m = fmaxf(m, Shi[k]);
        }
        m = fmaxf(m, __shfl_xor(m, 32, 64));       // combine hi5 halves
        float den = 0.f;
        float plo[16], phi[16];
        #pragma unroll
        for (int k = 0; k < 16; ++k) {
            const int jl = (k & 3) + 8 * (k >> 2) + 4 * hi5;
            const int jh = jl + 9;
            plo[k] = __expf(Slo[k] - m);
            phi[k] = __expf(Shi[k] - m);
            if (jl <= 8 && jl >= q && jl >= jmin) den += plo[k];
            if (jh >= q && jh <= q + 9) den += phi[k];
        }
        den += __shfl_xor(den, 32, 64);
        const float inv = __builtin_amdgcn_rcpf(den);

        // zero own P row (halves split cols 0..23 / 24..47), then scatter
        {
            const uint4 z = {0u, 0u, 0u, 0u};
            *(uint4*)&Pbd[q][24 * hi5 + 0]  = z;
            *(uint4*)&Pbd[q][24 * hi5 + 8]  = z;
            *(uint4*)&Pbd[q][24 * hi5 + 16] = z;
        }
        #pragma unroll
        for (int k = 0; k < 16; ++k) {
            const int jl = (k & 3) + 8 * (k >> 2) + 4 * hi5;
            const int jh = jl + 9;
            if (jl <= 8 && jl >= q && jl >= jmin)
                Pbd[q][32 + jl] = bfr(plo[k] * inv);
            if (jh >= q && jh <= q + 9)
                Pbd[q][jh - 9] = bfr(phi[k] * inv);
        }

        // PV: cols 0..31 (chunk) K=32, cols 32..47 (prev+zero pad) K=16
        const s16x8 pa0 = *(const s16x8*)&Pbd[l31][8 * hi5];
        const s16x8 pa1 = *(const s16x8*)&Pbd[l31][16 + 8 * hi5];
        const s16x8 pa2 = *(const s16x8*)&Pbd[l31][32 + 8 * hi5];
        const s16x8 vb0 = *(const s16x8*)&Vtb[l31][8 * hi5];
        const s16x8 vb1 = *(const s16x8*)&Vtb[l31][16 + 8 * hi5];
        const s16x8 vb2 = *(const s16x8*)&Vtb[l31][32 + 8 * hi5];
        f32x16 OB = {};
        OB = __builtin_amdgcn_mfma_f32_32x32x16_bf16(pa0, vb0, OB, 0, 0, 0);
        OB = __builtin_amdgcn_mfma_f32_32x32x16_bf16(pa1, vb1, OB, 0, 0, 0);
        OB = __builtin_amdgcn_mfma_f32_32x32x16_bf16(pa2, vb2, OB, 0, 0, 0);

        const float w1v = W1[h * EE + l31];        // C/D col = lane = d
        #pragma unroll
        for (int k = 0; k < 16; ++k) {
            const int row = (k & 3) + 8 * (k >> 2) + 4 * hi5;  // = q
            Obb[row][l31] = bfr(w1v * OB[k]);
        }
    }
    __syncthreads();

    // ---------------- final combine + single store (cluster mapping) --------
    const float4 o1 = *(const float4*)&Ob1[r][d0];
    const float4 o2 = *(const float4*)&Ob2[r][d0];
    const ushort4 ob = *(const ushort4*)&Obb[r][d0];
    float4 o;
    o.x = bf2f(ob.x) + o1.x + o2.x;
    o.y = bf2f(ob.y) + o1.y + o2.y;
    o.z = bf2f(ob.z) + o1.z + o2.z;
    o.w = bf2f(ob.w) + o1.w + o2.w;
    *(float4*)&out[((n * LL + l) * HH + h) * EE + d0] = o;
}

extern "C" void kernel_launch(void* const* d_in, const int* in_sizes, int n_in,
                              void* d_out, int out_size, void* d_ws, size_t ws_size,
                              hipStream_t stream)
{
    (void)in_sizes; (void)n_in; (void)out_size; (void)ws_size;
    const float* Q  = (const float*)d_in[0];
    const float* K  = (const float*)d_in[1];
    const float* V  = (const float*)d_in[2];
    // d_in[3] = key_lengths: cancels mathematically (normalization over E)
    const float* W1 = (const float*)d_in[4];
    const float* W2 = (const float*)d_in[5];
    const float* W3 = (const float*)d_in[6];
    float* out = (float*)d_out;
    unsigned short* ws = (unsigned short*)d_ws;   // NB*REC*2 = ~4.3 MB scratch

    chunksum_kernel<<<NB,           256, 0, stream>>>(K, V, ws);
    prefix_kernel  <<<NN * HH * 11, 192, 0, stream>>>(ws);
    fused_kernel   <<<NB,           256, 0, stream>>>(Q, K, V, W1, W2, W3, ws, out);
}

// Round 14
// 85.556 us; speedup vs baseline: 1.3399x; 1.0227x over previous
//
#include <hip/hip_runtime.h>
#include <cmath>

// Problem constants (fixed by setup_inputs)
constexpr int NN = 2;       // batch
constexpr int LL = 2048;    // sequence
constexpr int HH = 8;       // heads
constexpr int EE = 32;      // feature dim == value dim
constexpr int CC = 32;      // chunk length
constexpr int NCH = LL / CC;       // 64 chunks per (n,h)
constexpr int NB  = NN * HH * NCH; // 1024 blocks
constexpr int BWD = 10;     // softmax bandwidth
// bf16 record per chunk (shorts): St1[d][e] 32x32, k1[32], St2, k2
constexpr int REC  = 2 * (EE * EE + EE);   // 2112 shorts = 4224 B
constexpr int R16  = REC * 2 / 16;         // 264 16-byte slots
constexpr int OFF_S1 = 0, OFF_K1 = 1024, OFF_S2 = 1056, OFF_K2 = 2080; // short idx
constexpr int SK = EE + 4;   // 36: float4-aligned f32 row stride (144 B)
constexpr int SB = 40;       // bf16 LDS row stride (80 B, 16B-aligned rows)
constexpr int VS = 48;       // Vtb/Pband col count (96 B rows, 16B-aligned)

using f32x16 = __attribute__((ext_vector_type(16))) float;
using s16x8  = __attribute__((ext_vector_type(8)))  short;

__device__ __forceinline__ float elu1(float x) {
    return x > 0.f ? x + 1.f : __expf(x);   // elu(x)+1
}
// f32 -> bf16 bits, round-to-nearest-even (inputs finite)
__device__ __forceinline__ unsigned short bfr(float x) {
    union { float f; unsigned u; } v; v.f = x;
    return (unsigned short)((v.u + 0x7FFFu + ((v.u >> 16) & 1u)) >> 16);
}
__device__ __forceinline__ float bf2f(unsigned short b) {
    union { unsigned u; float f; } v; v.u = ((unsigned)b) << 16;
    return v.f;
}

// ---------------- Kernel 1: per-chunk state sums via MFMA --------------------
// R14: operand-SWAPPED S-MFMA (A=KnT rows(e), B=VT cols(d)) -> C/D col=lane=d,
// row=e: record write becomes 4x b64 stores (was 16 scalar 2B stores).
// launch_bounds(256,4) pins 4 blocks/CU.
__global__ __launch_bounds__(256, 4) void chunksum_kernel(
    const float* __restrict__ Kin, const float* __restrict__ Vin,
    unsigned short* __restrict__ ws)
{
    __shared__ __align__(16) unsigned short K1T[EE][SB];  // [e][j]
    __shared__ __align__(16) unsigned short K2T[EE][SB];  // [e][j]
    __shared__ __align__(16) unsigned short VT [EE][SB];  // [d][j]

    const int b  = blockIdx.x;
    const int c  = b & (NCH - 1);
    const int nh = b >> 6;
    const int t  = threadIdx.x;
    const int lane = t & 31;
    const int grp  = t >> 5;    // 0..7

    for (int r = grp; r < CC; r += 8) {
        const int l = c * CC + r;
        const int base = ((nh >> 3) * LL + l) * HH * EE + (nh & 7) * EE + lane;
        const float k = Kin[base];
        const float v = Vin[base];
        const float f1 = elu1(k);
        const float f2 = f1 * f1;
        float s1 = f1, s2 = f2;
        #pragma unroll
        for (int m = 1; m < 32; m <<= 1) {
            s1 += __shfl_xor(s1, m, 32);
            s2 += __shfl_xor(s2, m, 32);
        }
        K1T[lane][r] = bfr(f1 * __builtin_amdgcn_rcpf(s1));   // s1,s2 > 0
        K2T[lane][r] = bfr(f2 * __builtin_amdgcn_rcpf(s2));
        VT [lane][r] = bfr(v);
    }
    __syncthreads();

    const int wid = t >> 6;         // 0..3
    const int l64 = t & 63;
    const int l31 = l64 & 31;
    const int hi5 = l64 >> 5;       // k-half selector

    if (wid < 2) {                  // wave 0: branch 1, wave 1: branch 2
        const unsigned short* KT = wid ? &K2T[0][0] : &K1T[0][0];
        const s16x8 va0 = *(const s16x8*)&VT[l31][8 * hi5];      // B: col=d
        const s16x8 va1 = *(const s16x8*)&VT[l31][16 + 8 * hi5];
        const s16x8 kb0 = *(const s16x8*)&KT[l31 * SB + 8 * hi5]; // A: row=e
        const s16x8 kb1 = *(const s16x8*)&KT[l31 * SB + 16 + 8 * hi5];
        s16x8 ones;
        #pragma unroll
        for (int i = 0; i < 8; ++i) ones[i] = (short)0x3F80;  // bf16 1.0

        // S' = KnT x V^T : C/D col=lane=d, row(k)=e
        f32x16 S = {};
        S = __builtin_amdgcn_mfma_f32_32x32x16_bf16(kb0, va0, S, 0, 0, 0);
        S = __builtin_amdgcn_mfma_f32_32x32x16_bf16(kb1, va1, S, 0, 0, 0);
        // Dk (unchanged form): col=lane=e -> ks[e] lane-scalar
        f32x16 Dk = {};
        Dk = __builtin_amdgcn_mfma_f32_32x32x16_bf16(ones, kb0, Dk, 0, 0, 0);
        Dk = __builtin_amdgcn_mfma_f32_32x32x16_bf16(ones, kb1, Dk, 0, 0, 0);

        unsigned short* wb = ws + (size_t)b * REC + (wid ? OFF_S2 : OFF_S1);
        unsigned short* wk = ws + (size_t)b * REC + (wid ? OFF_K2 : OFF_K1);
        // record St[d][e]: lane=d owns row d; e=(k&3)+8*(k>>2)+4*hi5 ->
        // per k-group g: 4 consecutive e -> one b64 store
        #pragma unroll
        for (int g = 0; g < 4; ++g) {
            ushort4 o = { bfr(S[4*g+0]), bfr(S[4*g+1]), bfr(S[4*g+2]), bfr(S[4*g+3]) };
            *(ushort4*)&wb[l31 * EE + 8 * g + 4 * hi5] = o;
        }
        if (hi5 == 0) wk[l31] = bfr(Dk[0]);   // ks[e]
    }
}

// ---------------- Kernel 2: exclusive prefix over chunks (bf16, f32 carry) --
__global__ __launch_bounds__(192) void prefix_kernel(unsigned short* __restrict__ ws)
{
    const int g = blockIdx.x / 11;
    const int e = (blockIdx.x % 11) * 192 + threadIdx.x;   // 0..2111
    unsigned short* base = ws + (size_t)g * NCH * REC + e;
    float run = 0.f;
    {
        unsigned short v[32];
        #pragma unroll
        for (int c = 0; c < 32; ++c) v[c] = base[(size_t)c * REC];
        #pragma unroll
        for (int c = 0; c < 32; ++c) {
            base[(size_t)c * REC] = bfr(run);
            run += bf2f(v[c]);
        }
    }
    {
        unsigned short v[32];
        #pragma unroll
        for (int c = 0; c < 32; ++c) v[c] = base[(size_t)(32 + c) * REC];
        #pragma unroll
        for (int c = 0; c < 32; ++c) {
            base[(size_t)(32 + c) * REC] = bfr(run);
            run += bf2f(v[c]);
        }
    }
}

// ---------------- Kernel 3: all-MFMA fused -----------------------------------
// R14: __launch_bounds__(256,4) caps VGPR at 128 (4 blocks/CU guaranteed —
// occupancy probe); band uses TWO-PASS exp (den-pass inline, scatter-pass
// recomputes) killing the plo/phi register arrays (-32 VGPR on the band path).
__global__ __launch_bounds__(256, 4) void fused_kernel(
    const float* __restrict__ Qin, const float* __restrict__ Kin,
    const float* __restrict__ Vin,
    const float* __restrict__ W1, const float* __restrict__ W2,
    const float* __restrict__ W3, const unsigned short* __restrict__ ws,
    float* __restrict__ out)
{
    __shared__ __align__(16) unsigned short Qfb[CC][SB];   // bf16 elu1(Q)
    __shared__ __align__(16) unsigned short Kfb[CC][SB];   // bf16 elu1(K)
    __shared__ __align__(16) unsigned short Qrb[CC][SB];   // bf16 Q*temp (band)
    __shared__ __align__(16) unsigned short Krb[41][SB];   // bf16 raw K rows l0-9..l0+31
    __shared__ __align__(16) unsigned short Vtb[EE][VS];   // bf16 V^T: cols 0..31 chunk, 32..40 prev, 41..47 zero
    __shared__ __align__(16) unsigned short Pb1[CC][SB];   // P relayout (branch 1)
    __shared__ __align__(16) unsigned short Pb2[CC][SB];   // P relayout (branch 2)
    __shared__ __align__(16) unsigned short Pbd[CC][VS];   // band P relayout
    __shared__ __align__(16) unsigned short Obb[CC][SB];   // band output bf16
    __shared__ float Ob1[CC][SK];          // branch outputs f32 (w*z applied)
    __shared__ float Ob2[CC][SK];

    const int b  = blockIdx.x;
    const int c  = b & (NCH - 1);
    const int nh = b >> 6;
    const int h  = nh & 7;
    const int n  = nh >> 3;
    const int l0 = c * CC;
    const int t  = threadIdx.x;

    // ---------------- Phase A: vectorized staging ---------------------------
    const float temp = 0.17677669529663687f;   // 1/sqrt(32), folded into Qrb
    const int r   = t >> 3;        // row 0..31
    const int sub = t & 7;
    const int d0  = sub * 4;       // col quad
    const int l   = l0 + r;
    {
        const int base = ((n * LL + l) * HH + h) * EE + d0;
        const float4 k4 = *(const float4*)&Kin[base];
        const float4 v4 = *(const float4*)&Vin[base];
        const float4 q4 = *(const float4*)&Qin[base];
        ushort4 kf = { bfr(elu1(k4.x)), bfr(elu1(k4.y)), bfr(elu1(k4.z)), bfr(elu1(k4.w)) };
        ushort4 qf = { bfr(elu1(q4.x)), bfr(elu1(q4.y)), bfr(elu1(q4.z)), bfr(elu1(q4.w)) };
        ushort4 qr = { bfr(q4.x * temp), bfr(q4.y * temp), bfr(q4.z * temp), bfr(q4.w * temp) };
        ushort4 kr = { bfr(k4.x), bfr(k4.y), bfr(k4.z), bfr(k4.w) };
        *(ushort4*)&Kfb[r][d0] = kf;
        *(ushort4*)&Qfb[r][d0] = qf;
        *(ushort4*)&Qrb[r][d0] = qr;
        *(ushort4*)&Krb[9 + r][d0] = kr;
        Vtb[d0 + 0][r] = bfr(v4.x);
        Vtb[d0 + 1][r] = bfr(v4.y);
        Vtb[d0 + 2][r] = bfr(v4.z);
        Vtb[d0 + 3][r] = bfr(v4.w);
    }
    // previous 9 rows of raw K,V (zero-padded at sequence start)
    if (t < 72) {
        const int rr = t >> 3, dd0 = (t & 7) * 4;
        const int lp = l0 - 9 + rr;
        float4 k4 = {0.f, 0.f, 0.f, 0.f};
        float4 v4 = {0.f, 0.f, 0.f, 0.f};
        if (lp >= 0) {
            const int gbase = ((n * LL + lp) * HH + h) * EE + dd0;
            k4 = *(const float4*)&Kin[gbase];
            v4 = *(const float4*)&Vin[gbase];
        }
        ushort4 kr = { bfr(k4.x), bfr(k4.y), bfr(k4.z), bfr(k4.w) };
        *(ushort4*)&Krb[rr][dd0] = kr;
        Vtb[dd0 + 0][32 + rr] = bfr(v4.x);
        Vtb[dd0 + 1][32 + rr] = bfr(v4.y);
        Vtb[dd0 + 2][32 + rr] = bfr(v4.z);
        Vtb[dd0 + 3][32 + rr] = bfr(v4.w);
    }
    // zero Vtb pad cols 41..47 (garbage here would poison the W1 PV mfma)
    if (t < 32) {
        #pragma unroll
        for (int cc = 41; cc < 48; ++cc) Vtb[t][cc] = 0;
    }
    __syncthreads();

    const int wid = t >> 6;
    const int l64 = t & 63;
    const int l31 = l64 & 31;
    const int hi5 = l64 >> 5;

    if ((wid & 1) == 0) {
        // ------------- linear branches via MFMA (R10-verified chain) --------
        const bool b2 = (wid == 2);
        // S/k fragments DIRECT from global ws (L2-hot exclusive-prefix record)
        const unsigned short* SptG = ws + (size_t)b * REC + (b2 ? OFF_S2 : OFF_S1);
        const unsigned short* kpG  = ws + (size_t)b * REC + (b2 ? OFF_K2 : OFF_K1);
        const float* Wv = b2 ? W3 : W2;
        unsigned short* Pb = b2 ? &Pb2[0][0] : &Pb1[0][0];
        float* Ob = b2 ? &Ob2[0][0] : &Ob1[0][0];

        const s16x8 sb0 = *(const s16x8*)&SptG[l31 * EE + 8 * hi5];   // 16B global
        const s16x8 sb1 = *(const s16x8*)&SptG[l31 * EE + 16 + 8 * hi5];
        const s16x8 rb0 = *(const s16x8*)&kpG[8 * hi5];
        const s16x8 rb1 = *(const s16x8*)&kpG[16 + 8 * hi5];

        s16x8 qa0 = *(const s16x8*)&Qfb[l31][8 * hi5];
        s16x8 qa1 = *(const s16x8*)&Qfb[l31][16 + 8 * hi5];
        s16x8 kb0 = *(const s16x8*)&Kfb[l31][8 * hi5];
        s16x8 kb1 = *(const s16x8*)&Kfb[l31][16 + 8 * hi5];
        if (b2) {
            #pragma unroll
            for (int i = 0; i < 8; ++i) {
                float f;
                f = bf2f((unsigned short)qa0[i]); qa0[i] = (short)bfr(f * f);
                f = bf2f((unsigned short)qa1[i]); qa1[i] = (short)bfr(f * f);
                f = bf2f((unsigned short)kb0[i]); kb0[i] = (short)bfr(f * f);
                f = bf2f((unsigned short)kb1[i]); kb1[i] = (short)bfr(f * f);
            }
        }
        s16x8 ones;
        #pragma unroll
        for (int i = 0; i < 8; ++i) ones[i] = (short)0x3F80;  // bf16 1.0

        f32x16 Dk = {};
        Dk = __builtin_amdgcn_mfma_f32_32x32x16_bf16(ones, kb0, Dk, 0, 0, 0);
        Dk = __builtin_amdgcn_mfma_f32_32x32x16_bf16(ones, kb1, Dk, 0, 0, 0);
        f32x16 P = {};
        P = __builtin_amdgcn_mfma_f32_32x32x16_bf16(qa0, kb0, P, 0, 0, 0);
        P = __builtin_amdgcn_mfma_f32_32x32x16_bf16(qa1, kb1, P, 0, 0, 0);

        const float ki = __builtin_amdgcn_rcpf(Dk[0]);   // 1/sk[l31]
        #pragma unroll
        for (int k = 0; k < 16; ++k) {
            const int row = (k & 3) + 8 * (k >> 2) + 4 * hi5;
            Pb[row * SB + l31] = bfr((l31 <= row) ? P[k] * ki : 0.f);
        }
        const s16x8 pa0 = *(const s16x8*)&Pb[l31 * SB + 8 * hi5];
        const s16x8 pa1 = *(const s16x8*)&Pb[l31 * SB + 16 + 8 * hi5];

        const s16x8 vb0 = *(const s16x8*)&Vtb[l31][8 * hi5];
        const s16x8 vb1 = *(const s16x8*)&Vtb[l31][16 + 8 * hi5];

        f32x16 A = {};
        A = __builtin_amdgcn_mfma_f32_32x32x16_bf16(pa0, vb0, A, 0, 0, 0);
        A = __builtin_amdgcn_mfma_f32_32x32x16_bf16(pa1, vb1, A, 0, 0, 0);
        A = __builtin_amdgcn_mfma_f32_32x32x16_bf16(qa0, sb0, A, 0, 0, 0);
        A = __builtin_amdgcn_mfma_f32_32x32x16_bf16(qa1, sb1, A, 0, 0, 0);

        f32x16 Dp = {};
        Dp = __builtin_amdgcn_mfma_f32_32x32x16_bf16(pa0, ones, Dp, 0, 0, 0);
        Dp = __builtin_amdgcn_mfma_f32_32x32x16_bf16(pa1, ones, Dp, 0, 0, 0);
        Dp = __builtin_amdgcn_mfma_f32_32x32x16_bf16(qa0, rb0, Dp, 0, 0, 0);
        Dp = __builtin_amdgcn_mfma_f32_32x32x16_bf16(qa1, rb1, Dp, 0, 0, 0);

        const float wv = Wv[h * EE + l31];
        #pragma unroll
        for (int k = 0; k < 16; ++k) {
            const int row = (k & 3) + 8 * (k >> 2) + 4 * hi5;
            Ob[row * SK + l31] = wv * A[k] * __builtin_amdgcn_rcpf(Dp[k]);
        }
    } else if (wid == 1) {
        // ------------- band via MFMA (two-pass exp, no p-arrays) ------------
        const int q = l31;                         // query row (= C/D col)
        const int jmin = (l0 >= 9) ? 0 : 9 - l0;   // first valid Krb index
        const s16x8 qb0 = *(const s16x8*)&Qrb[q][8 * hi5];
        const s16x8 qb1 = *(const s16x8*)&Qrb[q][16 + 8 * hi5];
        const s16x8 kl0 = *(const s16x8*)&Krb[l31][8 * hi5];
        const s16x8 kl1 = *(const s16x8*)&Krb[l31][16 + 8 * hi5];
        const s16x8 kh0 = *(const s16x8*)&Krb[9 + l31][8 * hi5];
        const s16x8 kh1 = *(const s16x8*)&Krb[9 + l31][16 + 8 * hi5];

        f32x16 Slo = {}, Shi = {};
        Slo = __builtin_amdgcn_mfma_f32_32x32x16_bf16(kl0, qb0, Slo, 0, 0, 0);
        Slo = __builtin_amdgcn_mfma_f32_32x32x16_bf16(kl1, qb1, Slo, 0, 0, 0);
        Shi = __builtin_amdgcn_mfma_f32_32x32x16_bf16(kh0, qb0, Shi, 0, 0, 0);
        Shi = __builtin_amdgcn_mfma_f32_32x32x16_bf16(kh1, qb1, Shi, 0, 0, 0);

        // PARTITION: lo window owns jk<=8 only; hi window owns jk>=9.
        float m = -INFINITY;
        #pragma unroll
        for (int k = 0; k < 16; ++k) {
            const int jl = (k & 3) + 8 * (k >> 2) + 4 * hi5;
            const int jh = jl + 9;
            if (jl <= 8 && jl >= q && jl >= jmin) m = fmaxf(m, Slo[k]);
            if (jh >= q && jh <= q + 9) m = fmaxf(m, Shi[k]);
        }
        m = fmaxf(m, __shfl_xor(m, 32, 64));       // combine hi5 halves
        float den = 0.f;
        #pragma unroll
        for (int k = 0; k < 16; ++k) {
            const int jl = (k & 3) + 8 * (k >> 2) + 4 * hi5;
            const int jh = jl + 9;
            if (jl <= 8 && jl >= q && jl >= jmin) den += __expf(Slo[k] - m);
            if (jh >= q && jh <= q + 9) den += __expf(Shi[k] - m);
        }
        den += __shfl_xor(den, 32, 64);
        const float inv = __builtin_amdgcn_rcpf(den);

        // zero own P row (halves split cols 0..23 / 24..47), then scatter
        // (exp recomputed — rematerializable, keeps register count low)
        {
            const uint4 z = {0u, 0u, 0u, 0u};
            *(uint4*)&Pbd[q][24 * hi5 + 0]  = z;
            *(uint4*)&Pbd[q][24 * hi5 + 8]  = z;
            *(uint4*)&Pbd[q][24 * hi5 + 16] = z;
        }
        #pragma unroll
        for (int k = 0; k < 16; ++k) {
            const int jl = (k & 3) + 8 * (k >> 2) + 4 * hi5;
            const int jh = jl + 9;
            if (jl <= 8 && jl >= q && jl >= jmin)
                Pbd[q][32 + jl] = bfr(__expf(Slo[k] - m) * inv);
            if (jh >= q && jh <= q + 9)
                Pbd[q][jh - 9] = bfr(__expf(Shi[k] - m) * inv);
        }

        // PV: cols 0..31 (chunk) K=32, cols 32..47 (prev+zero pad) K=16
        const s16x8 pa0 = *(const s16x8*)&Pbd[l31][8 * hi5];
        const s16x8 pa1 = *(const s16x8*)&Pbd[l31][16 + 8 * hi5];
        const s16x8 pa2 = *(const s16x8*)&Pbd[l31][32 + 8 * hi5];
        const s16x8 vb0 = *(const s16x8*)&Vtb[l31][8 * hi5];
        const s16x8 vb1 = *(const s16x8*)&Vtb[l31][16 + 8 * hi5];
        const s16x8 vb2 = *(const s16x8*)&Vtb[l31][32 + 8 * hi5];
        f32x16 OB = {};
        OB = __builtin_amdgcn_mfma_f32_32x32x16_bf16(pa0, vb0, OB, 0, 0, 0);
        OB = __builtin_amdgcn_mfma_f32_32x32x16_bf16(pa1, vb1, OB, 0, 0, 0);
        OB = __builtin_amdgcn_mfma_f32_32x32x16_bf16(pa2, vb2, OB, 0, 0, 0);

        const float w1v = W1[h * EE + l31];        // C/D col = lane = d
        #pragma unroll
        for (int k = 0; k < 16; ++k) {
            const int row = (k & 3) + 8 * (k >> 2) + 4 * hi5;  // = q
            Obb[row][l31] = bfr(w1v * OB[k]);
        }
    }
    __syncthreads();

    // ---------------- final combine + single store (cluster mapping) --------
    const float4 o1 = *(const float4*)&Ob1[r][d0];
    const float4 o2 = *(const float4*)&Ob2[r][d0];
    const ushort4 ob = *(const ushort4*)&Obb[r][d0];
    float4 o;
    o.x = bf2f(ob.x) + o1.x + o2.x;
    o.y = bf2f(ob.y) + o1.y + o2.y;
    o.z = bf2f(ob.z) + o1.z + o2.z;
    o.w = bf2f(ob.w) + o1.w + o2.w;
    *(float4*)&out[((n * LL + l) * HH + h) * EE + d0] = o;
}

extern "C" void kernel_launch(void* const* d_in, const int* in_sizes, int n_in,
                              void* d_out, int out_size, void* d_ws, size_t ws_size,
                              hipStream_t stream)
{
    (void)in_sizes; (void)n_in; (void)out_size; (void)ws_size;
    const float* Q  = (const float*)d_in[0];
    const float* K  = (const float*)d_in[1];
    const float* V  = (const float*)d_in[2];
    // d_in[3] = key_lengths: cancels mathematically (normalization over E)
    const float* W1 = (const float*)d_in[4];
    const float* W2 = (const float*)d_in[5];
    const float* W3 = (const float*)d_in[6];
    float* out = (float*)d_out;
    unsigned short* ws = (unsigned short*)d_ws;   // NB*REC*2 = ~4.3 MB scratch

    chunksum_kernel<<<NB,           256, 0, stream>>>(K, V, ws);
    prefix_kernel  <<<NN * HH * 11, 192, 0, stream>>>(ws);
    fused_kernel   <<<NB,           256, 0, stream>>>(Q, K, V, W1, W2, W3, ws, out);
}

// Round 16
// 85.249 us; speedup vs baseline: 1.3447x; 1.0036x over previous
//
#include <hip/hip_runtime.h>
#include <cmath>

// Problem constants (fixed by setup_inputs)
constexpr int NN = 2;       // batch
constexpr int LL = 2048;    // sequence
constexpr int HH = 8;       // heads
constexpr int EE = 32;      // feature dim == value dim
constexpr int CC = 32;      // chunk length
constexpr int NCH = LL / CC;       // 64 chunks per (n,h)
constexpr int NB  = NN * HH * NCH; // 1024 blocks
constexpr int BWD = 10;     // softmax bandwidth
// bf16 record per chunk (shorts): St1[d][e] 32x32, k1[32], St2, k2
constexpr int REC  = 2 * (EE * EE + EE);   // 2112 shorts = 4224 B
constexpr int R16  = REC * 2 / 16;         // 264 16-byte slots
constexpr int OFF_S1 = 0, OFF_K1 = 1024, OFF_S2 = 1056, OFF_K2 = 2080; // short idx
constexpr int SK = EE + 4;   // 36: float4-aligned f32 row stride (144 B)
constexpr int SB = 40;       // bf16 LDS row stride (80 B, 16B-aligned rows)
constexpr int VS = 48;       // Vtb/Pband col count (96 B rows, 16B-aligned)

using f32x16 = __attribute__((ext_vector_type(16))) float;
using s16x8  = __attribute__((ext_vector_type(8)))  short;

__device__ __forceinline__ float elu1(float x) {
    return x > 0.f ? x + 1.f : __expf(x);   // elu(x)+1
}
// f32 -> bf16 bits, round-to-nearest-even (inputs finite)
__device__ __forceinline__ unsigned short bfr(float x) {
    union { float f; unsigned u; } v; v.f = x;
    return (unsigned short)((v.u + 0x7FFFu + ((v.u >> 16) & 1u)) >> 16);
}
__device__ __forceinline__ float bf2f(unsigned short b) {
    union { unsigned u; float f; } v; v.u = ((unsigned)b) << 16;
    return v.f;
}

// ---------------- Kernel 1: per-chunk state sums via MFMA --------------------
// R15: staging vectorized — thread=(row, e-quad): 2x float4 global loads +
// width-8 cluster shuffle reduce (6 shfl, was 8 scalar loads + 40 shfl).
__global__ __launch_bounds__(256, 4) void chunksum_kernel(
    const float* __restrict__ Kin, const float* __restrict__ Vin,
    unsigned short* __restrict__ ws)
{
    __shared__ __align__(16) unsigned short K1T[EE][SB];  // [e][j]
    __shared__ __align__(16) unsigned short K2T[EE][SB];  // [e][j]
    __shared__ __align__(16) unsigned short VT [EE][SB];  // [d][j]

    const int b  = blockIdx.x;
    const int c  = b & (NCH - 1);
    const int nh = b >> 6;
    const int t  = threadIdx.x;

    // staging: thread -> (row r, e-quad d0); 8-lane cluster owns one row
    {
        const int r  = t >> 3;
        const int d0 = (t & 7) * 4;
        const int l  = c * CC + r;
        const int base = ((nh >> 3) * LL + l) * HH * EE + (nh & 7) * EE + d0;
        const float4 k4 = *(const float4*)&Kin[base];
        const float4 v4 = *(const float4*)&Vin[base];
        const float f1x = elu1(k4.x), f1y = elu1(k4.y);
        const float f1z = elu1(k4.z), f1w = elu1(k4.w);
        const float f2x = f1x * f1x, f2y = f1y * f1y;
        const float f2z = f1z * f1z, f2w = f1w * f1w;
        float s1 = (f1x + f1y) + (f1z + f1w);
        float s2 = (f2x + f2y) + (f2z + f2w);
        #pragma unroll
        for (int m = 1; m < 8; m <<= 1) {
            s1 += __shfl_xor(s1, m, 8);
            s2 += __shfl_xor(s2, m, 8);
        }
        const float i1 = __builtin_amdgcn_rcpf(s1);   // s1,s2 > 0
        const float i2 = __builtin_amdgcn_rcpf(s2);
        K1T[d0 + 0][r] = bfr(f1x * i1); K1T[d0 + 1][r] = bfr(f1y * i1);
        K1T[d0 + 2][r] = bfr(f1z * i1); K1T[d0 + 3][r] = bfr(f1w * i1);
        K2T[d0 + 0][r] = bfr(f2x * i2); K2T[d0 + 1][r] = bfr(f2y * i2);
        K2T[d0 + 2][r] = bfr(f2z * i2); K2T[d0 + 3][r] = bfr(f2w * i2);
        VT [d0 + 0][r] = bfr(v4.x);     VT [d0 + 1][r] = bfr(v4.y);
        VT [d0 + 2][r] = bfr(v4.z);     VT [d0 + 3][r] = bfr(v4.w);
    }
    __syncthreads();

    const int wid = t >> 6;         // 0..3
    const int l64 = t & 63;
    const int l31 = l64 & 31;
    const int hi5 = l64 >> 5;       // k-half selector

    if (wid < 2) {                  // wave 0: branch 1, wave 1: branch 2
        const unsigned short* KT = wid ? &K2T[0][0] : &K1T[0][0];
        const s16x8 va0 = *(const s16x8*)&VT[l31][8 * hi5];      // B: col=d
        const s16x8 va1 = *(const s16x8*)&VT[l31][16 + 8 * hi5];
        const s16x8 kb0 = *(const s16x8*)&KT[l31 * SB + 8 * hi5]; // A: row=e
        const s16x8 kb1 = *(const s16x8*)&KT[l31 * SB + 16 + 8 * hi5];
        s16x8 ones;
        #pragma unroll
        for (int i = 0; i < 8; ++i) ones[i] = (short)0x3F80;  // bf16 1.0

        // S' = KnT x V^T : C/D col=lane=d, row(k)=e
        f32x16 S = {};
        S = __builtin_amdgcn_mfma_f32_32x32x16_bf16(kb0, va0, S, 0, 0, 0);
        S = __builtin_amdgcn_mfma_f32_32x32x16_bf16(kb1, va1, S, 0, 0, 0);
        // Dk: col=lane=e -> ks[e] lane-scalar
        f32x16 Dk = {};
        Dk = __builtin_amdgcn_mfma_f32_32x32x16_bf16(ones, kb0, Dk, 0, 0, 0);
        Dk = __builtin_amdgcn_mfma_f32_32x32x16_bf16(ones, kb1, Dk, 0, 0, 0);

        unsigned short* wb = ws + (size_t)b * REC + (wid ? OFF_S2 : OFF_S1);
        unsigned short* wk = ws + (size_t)b * REC + (wid ? OFF_K2 : OFF_K1);
        // record St[d][e]: lane=d owns row d; 4 consecutive e per k-group
        #pragma unroll
        for (int g = 0; g < 4; ++g) {
            ushort4 o = { bfr(S[4*g+0]), bfr(S[4*g+1]), bfr(S[4*g+2]), bfr(S[4*g+3]) };
            *(ushort4*)&wb[l31 * EE + 8 * g + 4 * hi5] = o;
        }
        if (hi5 == 0) wk[l31] = bfr(Dk[0]);   // ks[e]
    }
}

// ---------------- Kernel 2: split-scan exclusive prefix (bf16, f32 carry) ---
// R15: each scan lane split in two — half-0 thread scans chunks 0..31 and
// parks its f32 total in LDS; half-1 thread (same e) scans 32..63 seeded
// from it. Per-thread serial work halves; 2x waves (1056) for latency
// hiding. Summation order identical to the old 64-step loop -> bit-exact.
__global__ __launch_bounds__(192) void prefix_kernel(unsigned short* __restrict__ ws)
{
    __shared__ float tot[96];
    const int g   = blockIdx.x / 22;
    const int blk = blockIdx.x % 22;
    const int t   = threadIdx.x;
    const bool half = (t >= 96);
    const int e   = blk * 96 + (half ? t - 96 : t);   // 0..2111
    unsigned short* base = ws + (size_t)g * NCH * REC + e
                              + (half ? (size_t)32 * REC : 0);
    unsigned short v[32];
    #pragma unroll
    for (int c = 0; c < 32; ++c) v[c] = base[(size_t)c * REC];
    if (!half) {
        float run = 0.f;
        #pragma unroll
        for (int c = 0; c < 32; ++c) {
            base[(size_t)c * REC] = bfr(run);
            run += bf2f(v[c]);
        }
        tot[t] = run;
    }
    __syncthreads();
    if (half) {
        float run = tot[t - 96];
        #pragma unroll
        for (int c = 0; c < 32; ++c) {
            base[(size_t)c * REC] = bfr(run);
            run += bf2f(v[c]);
        }
    }
}

// ---------------- Kernel 3: all-MFMA fused (R14, verified) -------------------
__global__ __launch_bounds__(256, 4) void fused_kernel(
    const float* __restrict__ Qin, const float* __restrict__ Kin,
    const float* __restrict__ Vin,
    const float* __restrict__ W1, const float* __restrict__ W2,
    const float* __restrict__ W3, const unsigned short* __restrict__ ws,
    float* __restrict__ out)
{
    __shared__ __align__(16) unsigned short Qfb[CC][SB];   // bf16 elu1(Q)
    __shared__ __align__(16) unsigned short Kfb[CC][SB];   // bf16 elu1(K)
    __shared__ __align__(16) unsigned short Qrb[CC][SB];   // bf16 Q*temp (band)
    __shared__ __align__(16) unsigned short Krb[41][SB];   // bf16 raw K rows l0-9..l0+31
    __shared__ __align__(16) unsigned short Vtb[EE][VS];   // bf16 V^T: cols 0..31 chunk, 32..40 prev, 41..47 zero
    __shared__ __align__(16) unsigned short Pb1[CC][SB];   // P relayout (branch 1)
    __shared__ __align__(16) unsigned short Pb2[CC][SB];   // P relayout (branch 2)
    __shared__ __align__(16) unsigned short Pbd[CC][VS];   // band P relayout
    __shared__ __align__(16) unsigned short Obb[CC][SB];   // band output bf16
    __shared__ float Ob1[CC][SK];          // branch outputs f32 (w*z applied)
    __shared__ float Ob2[CC][SK];

    const int b  = blockIdx.x;
    const int c  = b & (NCH - 1);
    const int nh = b >> 6;
    const int h  = nh & 7;
    const int n  = nh >> 3;
    const int l0 = c * CC;
    const int t  = threadIdx.x;

    // ---------------- Phase A: vectorized staging ---------------------------
    const float temp = 0.17677669529663687f;   // 1/sqrt(32), folded into Qrb
    const int r   = t >> 3;        // row 0..31
    const int sub = t & 7;
    const int d0  = sub * 4;       // col quad
    const int l   = l0 + r;
    {
        const int base = ((n * LL + l) * HH + h) * EE + d0;
        const float4 k4 = *(const float4*)&Kin[base];
        const float4 v4 = *(const float4*)&Vin[base];
        const float4 q4 = *(const float4*)&Qin[base];
        ushort4 kf = { bfr(elu1(k4.x)), bfr(elu1(k4.y)), bfr(elu1(k4.z)), bfr(elu1(k4.w)) };
        ushort4 qf = { bfr(elu1(q4.x)), bfr(elu1(q4.y)), bfr(elu1(q4.z)), bfr(elu1(q4.w)) };
        ushort4 qr = { bfr(q4.x * temp), bfr(q4.y * temp), bfr(q4.z * temp), bfr(q4.w * temp) };
        ushort4 kr = { bfr(k4.x), bfr(k4.y), bfr(k4.z), bfr(k4.w) };
        *(ushort4*)&Kfb[r][d0] = kf;
        *(ushort4*)&Qfb[r][d0] = qf;
        *(ushort4*)&Qrb[r][d0] = qr;
        *(ushort4*)&Krb[9 + r][d0] = kr;
        Vtb[d0 + 0][r] = bfr(v4.x);
        Vtb[d0 + 1][r] = bfr(v4.y);
        Vtb[d0 + 2][r] = bfr(v4.z);
        Vtb[d0 + 3][r] = bfr(v4.w);
    }
    // previous 9 rows of raw K,V (zero-padded at sequence start)
    if (t < 72) {
        const int rr = t >> 3, dd0 = (t & 7) * 4;
        const int lp = l0 - 9 + rr;
        float4 k4 = {0.f, 0.f, 0.f, 0.f};
        float4 v4 = {0.f, 0.f, 0.f, 0.f};
        if (lp >= 0) {
            const int gbase = ((n * LL + lp) * HH + h) * EE + dd0;
            k4 = *(const float4*)&Kin[gbase];
            v4 = *(const float4*)&Vin[gbase];
        }
        ushort4 kr = { bfr(k4.x), bfr(k4.y), bfr(k4.z), bfr(k4.w) };
        *(ushort4*)&Krb[rr][dd0] = kr;
        Vtb[dd0 + 0][32 + rr] = bfr(v4.x);
        Vtb[dd0 + 1][32 + rr] = bfr(v4.y);
        Vtb[dd0 + 2][32 + rr] = bfr(v4.z);
        Vtb[dd0 + 3][32 + rr] = bfr(v4.w);
    }
    // zero Vtb pad cols 41..47 (garbage here would poison the W1 PV mfma)
    if (t < 32) {
        #pragma unroll
        for (int cc = 41; cc < 48; ++cc) Vtb[t][cc] = 0;
    }
    __syncthreads();

    const int wid = t >> 6;
    const int l64 = t & 63;
    const int l31 = l64 & 31;
    const int hi5 = l64 >> 5;

    if ((wid & 1) == 0) {
        // ------------- linear branches via MFMA (R10-verified chain) --------
        const bool b2 = (wid == 2);
        // S/k fragments DIRECT from global ws (L2-hot exclusive-prefix record)
        const unsigned short* SptG = ws + (size_t)b * REC + (b2 ? OFF_S2 : OFF_S1);
        const unsigned short* kpG  = ws + (size_t)b * REC + (b2 ? OFF_K2 : OFF_K1);
        const float* Wv = b2 ? W3 : W2;
        unsigned short* Pb = b2 ? &Pb2[0][0] : &Pb1[0][0];
        float* Ob = b2 ? &Ob2[0][0] : &Ob1[0][0];

        const s16x8 sb0 = *(const s16x8*)&SptG[l31 * EE + 8 * hi5];   // 16B global
        const s16x8 sb1 = *(const s16x8*)&SptG[l31 * EE + 16 + 8 * hi5];
        const s16x8 rb0 = *(const s16x8*)&kpG[8 * hi5];
        const s16x8 rb1 = *(const s16x8*)&kpG[16 + 8 * hi5];

        s16x8 qa0 = *(const s16x8*)&Qfb[l31][8 * hi5];
        s16x8 qa1 = *(const s16x8*)&Qfb[l31][16 + 8 * hi5];
        s16x8 kb0 = *(const s16x8*)&Kfb[l31][8 * hi5];
        s16x8 kb1 = *(const s16x8*)&Kfb[l31][16 + 8 * hi5];
        if (b2) {
            #pragma unroll
            for (int i = 0; i < 8; ++i) {
                float f;
                f = bf2f((unsigned short)qa0[i]); qa0[i] = (short)bfr(f * f);
                f = bf2f((unsigned short)qa1[i]); qa1[i] = (short)bfr(f * f);
                f = bf2f((unsigned short)kb0[i]); kb0[i] = (short)bfr(f * f);
                f = bf2f((unsigned short)kb1[i]); kb1[i] = (short)bfr(f * f);
            }
        }
        s16x8 ones;
        #pragma unroll
        for (int i = 0; i < 8; ++i) ones[i] = (short)0x3F80;  // bf16 1.0

        f32x16 Dk = {};
        Dk = __builtin_amdgcn_mfma_f32_32x32x16_bf16(ones, kb0, Dk, 0, 0, 0);
        Dk = __builtin_amdgcn_mfma_f32_32x32x16_bf16(ones, kb1, Dk, 0, 0, 0);
        f32x16 P = {};
        P = __builtin_amdgcn_mfma_f32_32x32x16_bf16(qa0, kb0, P, 0, 0, 0);
        P = __builtin_amdgcn_mfma_f32_32x32x16_bf16(qa1, kb1, P, 0, 0, 0);

        const float ki = __builtin_amdgcn_rcpf(Dk[0]);   // 1/sk[l31]
        #pragma unroll
        for (int k = 0; k < 16; ++k) {
            const int row = (k & 3) + 8 * (k >> 2) + 4 * hi5;
            Pb[row * SB + l31] = bfr((l31 <= row) ? P[k] * ki : 0.f);
        }
        const s16x8 pa0 = *(const s16x8*)&Pb[l31 * SB + 8 * hi5];
        const s16x8 pa1 = *(const s16x8*)&Pb[l31 * SB + 16 + 8 * hi5];

        const s16x8 vb0 = *(const s16x8*)&Vtb[l31][8 * hi5];
        const s16x8 vb1 = *(const s16x8*)&Vtb[l31][16 + 8 * hi5];

        f32x16 A = {};
        A = __builtin_amdgcn_mfma_f32_32x32x16_bf16(pa0, vb0, A, 0, 0, 0);
        A = __builtin_amdgcn_mfma_f32_32x32x16_bf16(pa1, vb1, A, 0, 0, 0);
        A = __builtin_amdgcn_mfma_f32_32x32x16_bf16(qa0, sb0, A, 0, 0, 0);
        A = __builtin_amdgcn_mfma_f32_32x32x16_bf16(qa1, sb1, A, 0, 0, 0);

        f32x16 Dp = {};
        Dp = __builtin_amdgcn_mfma_f32_32x32x16_bf16(pa0, ones, Dp, 0, 0, 0);
        Dp = __builtin_amdgcn_mfma_f32_32x32x16_bf16(pa1, ones, Dp, 0, 0, 0);
        Dp = __builtin_amdgcn_mfma_f32_32x32x16_bf16(qa0, rb0, Dp, 0, 0, 0);
        Dp = __builtin_amdgcn_mfma_f32_32x32x16_bf16(qa1, rb1, Dp, 0, 0, 0);

        const float wv = Wv[h * EE + l31];
        #pragma unroll
        for (int k = 0; k < 16; ++k) {
            const int row = (k & 3) + 8 * (k >> 2) + 4 * hi5;
            Ob[row * SK + l31] = wv * A[k] * __builtin_amdgcn_rcpf(Dp[k]);
        }
    } else if (wid == 1) {
        // ------------- band via MFMA (two-pass exp, partitioned windows) ----
        const int q = l31;                         // query row (= C/D col)
        const int jmin = (l0 >= 9) ? 0 : 9 - l0;   // first valid Krb index
        const s16x8 qb0 = *(const s16x8*)&Qrb[q][8 * hi5];
        const s16x8 qb1 = *(const s16x8*)&Qrb[q][16 + 8 * hi5];
        const s16x8 kl0 = *(const s16x8*)&Krb[l31][8 * hi5];
        const s16x8 kl1 = *(const s16x8*)&Krb[l31][16 + 8 * hi5];
        const s16x8 kh0 = *(const s16x8*)&Krb[9 + l31][8 * hi5];
        const s16x8 kh1 = *(const s16x8*)&Krb[9 + l31][16 + 8 * hi5];

        f32x16 Slo = {}, Shi = {};
        Slo = __builtin_amdgcn_mfma_f32_32x32x16_bf16(kl0, qb0, Slo, 0, 0, 0);
        Slo = __builtin_amdgcn_mfma_f32_32x32x16_bf16(kl1, qb1, Slo, 0, 0, 0);
        Shi = __builtin_amdgcn_mfma_f32_32x32x16_bf16(kh0, qb0, Shi, 0, 0, 0);
        Shi = __builtin_amdgcn_mfma_f32_32x32x16_bf16(kh1, qb1, Shi, 0, 0, 0);

        // PARTITION: lo window owns jk<=8 only; hi window owns jk>=9.
        float m = -INFINITY;
        #pragma unroll
        for (int k = 0; k < 16; ++k) {
            const int jl = (k & 3) + 8 * (k >> 2) + 4 * hi5;
            const int jh = jl + 9;
            if (jl <= 8 && jl >= q && jl >= jmin) m = fmaxf(m, Slo[k]);
            if (jh >= q && jh <= q + 9) m = fmaxf(m, Shi[k]);
        }
        m = fmaxf(m, __shfl_xor(m, 32, 64));       // combine hi5 halves
        float den = 0.f;
        #pragma unroll
        for (int k = 0; k < 16; ++k) {
            const int jl = (k & 3) + 8 * (k >> 2) + 4 * hi5;
            const int jh = jl + 9;
            if (jl <= 8 && jl >= q && jl >= jmin) den += __expf(Slo[k] - m);
            if (jh >= q && jh <= q + 9) den += __expf(Shi[k] - m);
        }
        den += __shfl_xor(den, 32, 64);
        const float inv = __builtin_amdgcn_rcpf(den);

        // zero own P row (halves split cols 0..23 / 24..47), then scatter
        {
            const uint4 z = {0u, 0u, 0u, 0u};
            *(uint4*)&Pbd[q][24 * hi5 + 0]  = z;
            *(uint4*)&Pbd[q][24 * hi5 + 8]  = z;
            *(uint4*)&Pbd[q][24 * hi5 + 16] = z;
        }
        #pragma unroll
        for (int k = 0; k < 16; ++k) {
            const int jl = (k & 3) + 8 * (k >> 2) + 4 * hi5;
            const int jh = jl + 9;
            if (jl <= 8 && jl >= q && jl >= jmin)
                Pbd[q][32 + jl] = bfr(__expf(Slo[k] - m) * inv);
            if (jh >= q && jh <= q + 9)
                Pbd[q][jh - 9] = bfr(__expf(Shi[k] - m) * inv);
        }

        // PV: cols 0..31 (chunk) K=32, cols 32..47 (prev+zero pad) K=16
        const s16x8 pa0 = *(const s16x8*)&Pbd[l31][8 * hi5];
        const s16x8 pa1 = *(const s16x8*)&Pbd[l31][16 + 8 * hi5];
        const s16x8 pa2 = *(const s16x8*)&Pbd[l31][32 + 8 * hi5];
        const s16x8 vb0 = *(const s16x8*)&Vtb[l31][8 * hi5];
        const s16x8 vb1 = *(const s16x8*)&Vtb[l31][16 + 8 * hi5];
        const s16x8 vb2 = *(const s16x8*)&Vtb[l31][32 + 8 * hi5];
        f32x16 OB = {};
        OB = __builtin_amdgcn_mfma_f32_32x32x16_bf16(pa0, vb0, OB, 0, 0, 0);
        OB = __builtin_amdgcn_mfma_f32_32x32x16_bf16(pa1, vb1, OB, 0, 0, 0);
        OB = __builtin_amdgcn_mfma_f32_32x32x16_bf16(pa2, vb2, OB, 0, 0, 0);

        const float w1v = W1[h * EE + l31];        // C/D col = lane = d
        #pragma unroll
        for (int k = 0; k < 16; ++k) {
            const int row = (k & 3) + 8 * (k >> 2) + 4 * hi5;  // = q
            Obb[row][l31] = bfr(w1v * OB[k]);
        }
    }
    __syncthreads();

    // ---------------- final combine + single store (cluster mapping) --------
    const float4 o1 = *(const float4*)&Ob1[r][d0];
    const float4 o2 = *(const float4*)&Ob2[r][d0];
    const ushort4 ob = *(const ushort4*)&Obb[r][d0];
    float4 o;
    o.x = bf2f(ob.x) + o1.x + o2.x;
    o.y = bf2f(ob.y) + o1.y + o2.y;
    o.z = bf2f(ob.z) + o1.z + o2.z;
    o.w = bf2f(ob.w) + o1.w + o2.w;
    *(float4*)&out[((n * LL + l) * HH + h) * EE + d0] = o;
}

extern "C" void kernel_launch(void* const* d_in, const int* in_sizes, int n_in,
                              void* d_out, int out_size, void* d_ws, size_t ws_size,
                              hipStream_t stream)
{
    (void)in_sizes; (void)n_in; (void)out_size; (void)ws_size;
    const float* Q  = (const float*)d_in[0];
    const float* K  = (const float*)d_in[1];
    const float* V  = (const float*)d_in[2];
    // d_in[3] = key_lengths: cancels mathematically (normalization over E)
    const float* W1 = (const float*)d_in[4];
    const float* W2 = (const float*)d_in[5];
    const float* W3 = (const float*)d_in[6];
    float* out = (float*)d_out;
    unsigned short* ws = (unsigned short*)d_ws;   // NB*REC*2 = ~4.3 MB scratch

    chunksum_kernel<<<NB,      256, 0, stream>>>(K, V, ws);
    prefix_kernel  <<<16 * 22, 192, 0, stream>>>(ws);
    fused_kernel   <<<NB,      256, 0, stream>>>(Q, K, V, W1, W2, W3, ws, out);
}